// Round 7
// baseline (1041.672 us; speedup 1.0000x reference)
//
#include <hip/hip_runtime.h>
#include <hip/hip_bf16.h>
#include <math.h>

#define B_   8
#define E_   256
#define N_   32
#define D_   512
#define RD_  768
#define R_   2000
#define L_   2
#define K_   8
#define M_   32
#define H_   8
#define DH_  64
#define HL_  4096

#define NBLK 512

typedef float f32x4 __attribute__((ext_vector_type(4)));
typedef __bf16 bf16x8 __attribute__((ext_vector_type(8)));
typedef const __attribute__((address_space(1))) void GVoid;
typedef __attribute__((address_space(3))) void LVoid;

__device__ __forceinline__ float gelu_exact(float x) {
    return 0.5f * x * (1.0f + erff(x * 0.70710678118654752f));
}
__device__ __forceinline__ unsigned short f2bf(float x) {
    return __hip_bfloat16_raw(__float2bfloat16(x)).x;
}

// ---------------------------------------------------------------------------
// Software grid barrier (R7): one dedicated counter per boundary, zeroed by
// hipMemsetAsync each launch. Device-scope atomics + agent fences (G16).
// Requires all blocks co-resident: grid=512, LDS 48KB (3/CU cap),
// __launch_bounds__(256,2) (VGPR<=256 -> >=2 blocks/CU). 512 = 2/CU exactly.
// ---------------------------------------------------------------------------
__device__ __forceinline__ void gbar(int* bar) {
    __syncthreads();                       // all waves drained their stores
    if (threadIdx.x == 0) {
        __threadfence();                   // release: L2 writeback
        __hip_atomic_fetch_add(bar, 1, __ATOMIC_RELEASE, __HIP_MEMORY_SCOPE_AGENT);
        while (__hip_atomic_load(bar, __ATOMIC_ACQUIRE, __HIP_MEMORY_SCOPE_AGENT) < NBLK)
            __builtin_amdgcn_s_sleep(2);
        __threadfence();                   // acquire: invalidate caches
    }
    __syncthreads();
}

// ---------------------------------------------------------------------------
// Device-side bf16 MFMA GEMM tile (R4 dbuf structure). One (bx,by,bz) tile of
// C[M,N] = A @ W^T [+bias]. BK=64, global_load_lds w=16, XOR chunk-swizzle.
// SPLITK>1: bz selects K-range, f32 partial -> Cv + bz*M*N, bias in bz==0.
// ---------------------------------------------------------------------------
template <int TM, int TN, int ACT_GELU, int OUT_BF16, int HAS_BIAS, int FLAGS, int SPLITK>
__device__ __forceinline__ void gemm_tile(int bx, int by, int bz,
        const unsigned short* __restrict__ A, const unsigned short* __restrict__ W,
        const float* __restrict__ bias, void* __restrict__ Cv,
        int M, int N, int K, const float* __restrict__ rowflag,
        unsigned short* smem) {
    constexpr int WTM = TM / 2, WTN = TN / 2;
    constexpr int RM = WTM / 16, RN = WTN / 16;
    constexpr int AI = TM / 32, BI = TN / 32;
    unsigned short* As = smem;
    unsigned short* Bs = smem + 2 * TM * 64;

    const int tid = threadIdx.x;
    const int wave = tid >> 6, lane = tid & 63;
    const int quad = lane >> 4, l16 = lane & 15;
    const int wm = wave >> 1, wn = wave & 1;
    const int bm = by * TM, bn = bx * TN;
    const int sub = lane >> 3;
    const int cpr = (lane & 7) ^ sub;

    f32x4 acc[RM][RN];
#pragma unroll
    for (int i = 0; i < RM; i++)
#pragma unroll
        for (int j = 0; j < RN; j++) acc[i][j] = (f32x4){0.f, 0.f, 0.f, 0.f};

    const int kspan = K / SPLITK;
    const int kb = bz * kspan;
    const int nt = kspan / 64;

    auto stage = [&](int k0, int buf) {
#pragma unroll
        for (int i = 0; i < AI; i++) {
            int r0 = (wave * AI + i) * 8;
            const unsigned short* g = A + (size_t)(bm + r0 + sub) * K + k0 + cpr * 8;
            __builtin_amdgcn_global_load_lds((GVoid*)g, (LVoid*)&As[buf * TM * 64 + r0 * 64], 16, 0, 0);
        }
#pragma unroll
        for (int i = 0; i < BI; i++) {
            int r0 = (wave * BI + i) * 8;
            const unsigned short* g = W + (size_t)(bn + r0 + sub) * K + k0 + cpr * 8;
            __builtin_amdgcn_global_load_lds((GVoid*)g, (LVoid*)&Bs[buf * TN * 64 + r0 * 64], 16, 0, 0);
        }
    };

    stage(kb, 0);
    __syncthreads();

    for (int t = 0; t < nt; t++) {
        const int cur = t & 1;
        if (t + 1 < nt) stage(kb + (t + 1) * 64, cur ^ 1);
#pragma unroll
        for (int h = 0; h < 2; h++) {
            bf16x8 af[RM], bf[RN];
#pragma unroll
            for (int i = 0; i < RM; i++) {
                int r = wm * WTM + i * 16 + l16;
                int ch = (h * 4 + quad) ^ (r & 7);
                af[i] = *(const bf16x8*)&As[cur * TM * 64 + r * 64 + ch * 8];
            }
#pragma unroll
            for (int j = 0; j < RN; j++) {
                int r = wn * WTN + j * 16 + l16;
                int ch = (h * 4 + quad) ^ (r & 7);
                bf[j] = *(const bf16x8*)&Bs[cur * TN * 64 + r * 64 + ch * 8];
            }
#pragma unroll
            for (int i = 0; i < RM; i++)
#pragma unroll
                for (int j = 0; j < RN; j++)
                    acc[i][j] = __builtin_amdgcn_mfma_f32_16x16x32_bf16(af[i], bf[j], acc[i][j], 0, 0, 0);
        }
        __syncthreads();
    }

    float* Cf = (float*)Cv + (size_t)bz * M * N;
#pragma unroll
    for (int i = 0; i < RM; i++) {
#pragma unroll
        for (int j = 0; j < RN; j++) {
            int c = bn + wn * WTN + j * 16 + l16;
            float bv = (HAS_BIAS && bz == 0) ? bias[c] : 0.f;
#pragma unroll
            for (int reg = 0; reg < 4; reg++) {
                int r = bm + wm * WTM + i * 16 + quad * 4 + reg;
                if (r < M) {
                    float v = acc[i][j][reg] + bv;
                    if (ACT_GELU) v = gelu_exact(v);
                    if (FLAGS) v *= rowflag[r >> 5];
                    if (OUT_BF16)
                        ((unsigned short*)Cv)[(size_t)r * N + c] = f2bf(v);
                    else
                        Cf[(size_t)r * N + c] = v;
                }
            }
        }
    }
}

// ---------------------------------------------------------------------------
// Wave-per-row LN (R6 structure): lane l owns elems l*8..l*8+7.
// ---------------------------------------------------------------------------
__device__ __forceinline__ void wave_ln(const float* __restrict__ xr,
                                        const float* __restrict__ yr,
                                        const float* __restrict__ y2r,
                                        const float* __restrict__ g,
                                        const float* __restrict__ bb, float mv,
                                        float* __restrict__ outf,
                                        unsigned short* __restrict__ outb, int lane) {
    int base = lane * 8;
    float v[8];
    {
        float4 xa = *(const float4*)(xr + base), xb = *(const float4*)(xr + base + 4);
        float4 ya = *(const float4*)(yr + base), yb = *(const float4*)(yr + base + 4);
        v[0] = xa.x + ya.x; v[1] = xa.y + ya.y; v[2] = xa.z + ya.z; v[3] = xa.w + ya.w;
        v[4] = xb.x + yb.x; v[5] = xb.y + yb.y; v[6] = xb.z + yb.z; v[7] = xb.w + yb.w;
    }
    if (y2r) {
        float4 za = *(const float4*)(y2r + base), zb = *(const float4*)(y2r + base + 4);
        v[0] += za.x; v[1] += za.y; v[2] += za.z; v[3] += za.w;
        v[4] += zb.x; v[5] += zb.y; v[6] += zb.z; v[7] += zb.w;
    }
    float s = ((v[0] + v[1]) + (v[2] + v[3])) + ((v[4] + v[5]) + (v[6] + v[7]));
#pragma unroll
    for (int off = 32; off; off >>= 1) s += __shfl_xor(s, off, 64);
    float mean = s * (1.f / 512.f);
    float d[8], q = 0.f;
#pragma unroll
    for (int j = 0; j < 8; j++) { d[j] = v[j] - mean; q += d[j] * d[j]; }
#pragma unroll
    for (int off = 32; off; off >>= 1) q += __shfl_xor(q, off, 64);
    float rs = rsqrtf(q * (1.f / 512.f) + 1e-5f);
    float4 ga = *(const float4*)(g + base), gb = *(const float4*)(g + base + 4);
    float4 ba = *(const float4*)(bb + base), bb4 = *(const float4*)(bb + base + 4);
    float o[8];
    o[0] = (d[0] * rs * ga.x + ba.x) * mv;  o[1] = (d[1] * rs * ga.y + ba.y) * mv;
    o[2] = (d[2] * rs * ga.z + ba.z) * mv;  o[3] = (d[3] * rs * ga.w + ba.w) * mv;
    o[4] = (d[4] * rs * gb.x + bb4.x) * mv; o[5] = (d[5] * rs * gb.y + bb4.y) * mv;
    o[6] = (d[6] * rs * gb.z + bb4.z) * mv; o[7] = (d[7] * rs * gb.w + bb4.w) * mv;
    if (outf) {
        *(float4*)(outf + base) = make_float4(o[0], o[1], o[2], o[3]);
        *(float4*)(outf + base + 4) = make_float4(o[4], o[5], o[6], o[7]);
    }
    union { unsigned short u[8]; uint4 q4; } pk;
#pragma unroll
    for (int j = 0; j < 8; j++) pk.u[j] = f2bf(o[j]);
    *(uint4*)(outb + base) = pk.q4;
}

// ---------------------------------------------------------------------------
// mem_attn tile (R5-proven batched-4 structure), LDS overlaid on smem.
// ---------------------------------------------------------------------------
__device__ __forceinline__ void mem_attn_tile(int idx, const float* __restrict__ qb,
        const float* __restrict__ kv, const float* __restrict__ mask,
        unsigned short* __restrict__ memb, unsigned short* smemraw) {
    float* SM = (float*)smemraw;
    float* qh = SM;              // [4][64]
    float* sc = SM + 256;        // [4][256]
    float* redm = SM + 1280;     // [4][4]
    float* reds = SM + 1296;     // [4][4]
    float* oacc = SM + 1312;     // [4][4][64]
    int b = idx & 7, h = (idx >> 3) & 7, mg = idx >> 6;
    int tid = threadIdx.x;

    { int i = tid >> 6, d = tid & 63; qh[i * 64 + d] = qb[(size_t)(mg * 4 + i) * D_ + h * DH_ + d]; }
    float mk = mask[b * E_ + tid];
    __syncthreads();

    const float* kr = kv + ((size_t)(b * E_ + tid)) * 1024 + h * DH_;
    float s0 = 0.f, s1 = 0.f, s2 = 0.f, s3 = 0.f;
#pragma unroll
    for (int d = 0; d < DH_; d += 4) {
        float4 k4 = *(const float4*)(kr + d);
        s0 += k4.x * qh[d] + k4.y * qh[d + 1] + k4.z * qh[d + 2] + k4.w * qh[d + 3];
        s1 += k4.x * qh[64 + d] + k4.y * qh[64 + d + 1] + k4.z * qh[64 + d + 2] + k4.w * qh[64 + d + 3];
        s2 += k4.x * qh[128 + d] + k4.y * qh[128 + d + 1] + k4.z * qh[128 + d + 2] + k4.w * qh[128 + d + 3];
        s3 += k4.x * qh[192 + d] + k4.y * qh[192 + d + 1] + k4.z * qh[192 + d + 2] + k4.w * qh[192 + d + 3];
    }
    s0 *= 0.125f; s1 *= 0.125f; s2 *= 0.125f; s3 *= 0.125f;
    if (mk == 0.f) { s0 = s1 = s2 = s3 = -3.402823466e38f; }

    int wid = tid >> 6;
    float m0 = s0, m1 = s1, m2 = s2, m3 = s3;
#pragma unroll
    for (int off = 32; off; off >>= 1) {
        m0 = fmaxf(m0, __shfl_xor(m0, off, 64));
        m1 = fmaxf(m1, __shfl_xor(m1, off, 64));
        m2 = fmaxf(m2, __shfl_xor(m2, off, 64));
        m3 = fmaxf(m3, __shfl_xor(m3, off, 64));
    }
    if ((tid & 63) == 0) { redm[wid * 4 + 0] = m0; redm[wid * 4 + 1] = m1; redm[wid * 4 + 2] = m2; redm[wid * 4 + 3] = m3; }
    __syncthreads();
    m0 = fmaxf(fmaxf(redm[0], redm[4]), fmaxf(redm[8], redm[12]));
    m1 = fmaxf(fmaxf(redm[1], redm[5]), fmaxf(redm[9], redm[13]));
    m2 = fmaxf(fmaxf(redm[2], redm[6]), fmaxf(redm[10], redm[14]));
    m3 = fmaxf(fmaxf(redm[3], redm[7]), fmaxf(redm[11], redm[15]));
    float p0 = expf(s0 - m0), p1 = expf(s1 - m1), p2 = expf(s2 - m2), p3 = expf(s3 - m3);
    float u0 = p0, u1 = p1, u2 = p2, u3 = p3;
#pragma unroll
    for (int off = 32; off; off >>= 1) {
        u0 += __shfl_xor(u0, off, 64);
        u1 += __shfl_xor(u1, off, 64);
        u2 += __shfl_xor(u2, off, 64);
        u3 += __shfl_xor(u3, off, 64);
    }
    if ((tid & 63) == 0) { reds[wid * 4 + 0] = u0; reds[wid * 4 + 1] = u1; reds[wid * 4 + 2] = u2; reds[wid * 4 + 3] = u3; }
    __syncthreads();
    u0 = reds[0] + reds[4] + reds[8] + reds[12];
    u1 = reds[1] + reds[5] + reds[9] + reds[13];
    u2 = reds[2] + reds[6] + reds[10] + reds[14];
    u3 = reds[3] + reds[7] + reds[11] + reds[15];
    sc[0 * 256 + tid] = p0 / u0;
    sc[1 * 256 + tid] = p1 / u1;
    sc[2 * 256 + tid] = p2 / u2;
    sc[3 * 256 + tid] = p3 / u3;
    __syncthreads();

    int d = tid & 63, part = tid >> 6;
    const float* vcol = kv + ((size_t)(b * E_ + part * 64)) * 1024 + 512 + h * DH_ + d;
    float a0 = 0.f, a1 = 0.f, a2 = 0.f, a3 = 0.f;
#pragma unroll 8
    for (int e = 0; e < 64; e++) {
        float vv = vcol[(size_t)e * 1024];
        a0 += sc[0 * 256 + part * 64 + e] * vv;
        a1 += sc[1 * 256 + part * 64 + e] * vv;
        a2 += sc[2 * 256 + part * 64 + e] * vv;
        a3 += sc[3 * 256 + part * 64 + e] * vv;
    }
    oacc[(part * 4 + 0) * 64 + d] = a0;
    oacc[(part * 4 + 1) * 64 + d] = a1;
    oacc[(part * 4 + 2) * 64 + d] = a2;
    oacc[(part * 4 + 3) * 64 + d] = a3;
    __syncthreads();
    if (part == 0) {
#pragma unroll
        for (int i = 0; i < 4; i++)
            memb[((size_t)(b * M_ + mg * 4 + i)) * D_ + h * DH_ + d] =
                f2bf(oacc[(0 * 4 + i) * 64 + d] + oacc[(1 * 4 + i) * 64 + d] +
                     oacc[(2 * 4 + i) * 64 + d] + oacc[(3 * 4 + i) * 64 + d]);
    }
}

// ---------------------------------------------------------------------------
// Mega-kernel (software-barrier version): steps 4..15, grid = 512 x 256.
// ---------------------------------------------------------------------------
struct MegaArgs {
    const unsigned short *agg, *wfuse, *w1, *w2, *kvw, *tow, *pw;
    const float *bfuse, *b1, *b2, *n1g, *n1b, *n2g, *n2b, *mask, *kvb, *qbuf,
                *tob, *projb, *flags, *proj;
    const int* eids;
    float *attnall, *statesX, *states, *tmpB;
    unsigned short *st, *ff1, *memb, *mem2;
    float* out;
    int* bar;                         // 16 zeroed counters
};

__global__ __launch_bounds__(256, 2) void mega_kernel(MegaArgs a) {
    __shared__ __align__(16) unsigned short SMEM[24576];   // 48 KiB
    const int tile = blockIdx.x;
    const int tid = threadIdx.x;
    const int wv = tid >> 6, lane = tid & 63;

    // P0: attn (both layers) = agg @ wfuse^T + bfuse -> attnall [2048,1024] f32
    gemm_tile<64, 64, 0, 0, 1, 0, 1>(tile & 15, tile >> 4, 0, a.agg, a.wfuse,
                                     a.bfuse, a.attnall, 2048, 1024, 512, nullptr, SMEM);
    gbar(a.bar + 0);

    // P1: LN1(l0): statesX = LN(proj[eid] + attn_l0); st = bf16
    {
        int t = (tile << 2) | wv;
        const float* xr = a.proj + (size_t)a.eids[t] * D_;
        const float* yr = a.attnall + (size_t)t * 1024;
        wave_ln(xr, yr, nullptr, a.n1g, a.n1b, 1.f,
                a.statesX + (size_t)t * D_, a.st + (size_t)t * D_, lane);
    }
    gbar(a.bar + 1);

    // P2: ff1(l0) 64x128 -> ff1 bf16 [2048,2048], GELU
    gemm_tile<64, 128, 1, 1, 1, 0, 1>(tile & 15, tile >> 4, 0, a.st, a.w1, a.b1,
                                      a.ff1, 2048, 2048, 512, nullptr, SMEM);
    gbar(a.bar + 2);

    // P3: ff2(l0) 64x64 split-K x2 -> tmpB partials f32
    { int r = tile & 255;
      gemm_tile<64, 64, 0, 0, 1, 0, 2>(r & 7, r >> 3, tile >> 8, a.ff1, a.w2, a.b2,
                                       a.tmpB, 2048, 512, 2048, nullptr, SMEM); }
    gbar(a.bar + 3);

    // P4: dbl LN -> states (f32) + st (bf16)
    {
        int t = (tile << 2) | wv;
        int base = lane * 8;
        const float* xr = a.statesX + (size_t)t * D_;
        const float* yr = a.tmpB + (size_t)t * D_;
        const float* zr = a.tmpB + (size_t)2048 * D_ + (size_t)t * D_;
        float v[8];
        {
            float4 xa = *(const float4*)(xr + base), xb = *(const float4*)(xr + base + 4);
            float4 ya = *(const float4*)(yr + base), yb = *(const float4*)(yr + base + 4);
            float4 za = *(const float4*)(zr + base), zb = *(const float4*)(zr + base + 4);
            v[0] = xa.x + ya.x + za.x; v[1] = xa.y + ya.y + za.y;
            v[2] = xa.z + ya.z + za.z; v[3] = xa.w + ya.w + za.w;
            v[4] = xb.x + yb.x + zb.x; v[5] = xb.y + yb.y + zb.y;
            v[6] = xb.z + yb.z + zb.z; v[7] = xb.w + yb.w + zb.w;
        }
        float s = ((v[0] + v[1]) + (v[2] + v[3])) + ((v[4] + v[5]) + (v[6] + v[7]));
#pragma unroll
        for (int off = 32; off; off >>= 1) s += __shfl_xor(s, off, 64);
        float mean = s * (1.f / 512.f);
        float d[8], q = 0.f;
#pragma unroll
        for (int j = 0; j < 8; j++) { d[j] = v[j] - mean; q += d[j] * d[j]; }
#pragma unroll
        for (int off = 32; off; off >>= 1) q += __shfl_xor(q, off, 64);
        float rs = rsqrtf(q * (1.f / 512.f) + 1e-5f);
        float mv = a.mask[t];
        float4 ga = *(const float4*)(a.n2g + base), gb = *(const float4*)(a.n2g + base + 4);
        float4 ba = *(const float4*)(a.n2b + base), bb4 = *(const float4*)(a.n2b + base + 4);
        const float* ar = a.attnall + (size_t)t * 1024 + 512;
        float4 aa = *(const float4*)(ar + base), ab = *(const float4*)(ar + base + 4);
        float w[8];
        w[0] = (d[0] * rs * ga.x + ba.x) * mv + aa.x;  w[1] = (d[1] * rs * ga.y + ba.y) * mv + aa.y;
        w[2] = (d[2] * rs * ga.z + ba.z) * mv + aa.z;  w[3] = (d[3] * rs * ga.w + ba.w) * mv + aa.w;
        w[4] = (d[4] * rs * gb.x + bb4.x) * mv + ab.x; w[5] = (d[5] * rs * gb.y + bb4.y) * mv + ab.y;
        w[6] = (d[6] * rs * gb.z + bb4.z) * mv + ab.z; w[7] = (d[7] * rs * gb.w + bb4.w) * mv + ab.w;
        float s2 = ((w[0] + w[1]) + (w[2] + w[3])) + ((w[4] + w[5]) + (w[6] + w[7]));
#pragma unroll
        for (int off = 32; off; off >>= 1) s2 += __shfl_xor(s2, off, 64);
        float mean2 = s2 * (1.f / 512.f);
        float e[8], q2 = 0.f;
#pragma unroll
        for (int j = 0; j < 8; j++) { e[j] = w[j] - mean2; q2 += e[j] * e[j]; }
#pragma unroll
        for (int off = 32; off; off >>= 1) q2 += __shfl_xor(q2, off, 64);
        float rs2 = rsqrtf(q2 * (1.f / 512.f) + 1e-5f);
        float4 g1a = *(const float4*)(a.n1g + 512 + base), g1b = *(const float4*)(a.n1g + 512 + base + 4);
        float4 b1a = *(const float4*)(a.n1b + 512 + base), b1b = *(const float4*)(a.n1b + 512 + base + 4);
        float o[8];
        o[0] = e[0] * rs2 * g1a.x + b1a.x; o[1] = e[1] * rs2 * g1a.y + b1a.y;
        o[2] = e[2] * rs2 * g1a.z + b1a.z; o[3] = e[3] * rs2 * g1a.w + b1a.w;
        o[4] = e[4] * rs2 * g1b.x + b1b.x; o[5] = e[5] * rs2 * g1b.y + b1b.y;
        o[6] = e[6] * rs2 * g1b.z + b1b.z; o[7] = e[7] * rs2 * g1b.w + b1b.w;
        float* outf = a.states + (size_t)t * D_;
        *(float4*)(outf + base) = make_float4(o[0], o[1], o[2], o[3]);
        *(float4*)(outf + base + 4) = make_float4(o[4], o[5], o[6], o[7]);
        union { unsigned short u[8]; uint4 q4; } pk;
#pragma unroll
        for (int j = 0; j < 8; j++) pk.u[j] = f2bf(o[j]);
        *(uint4*)(a.st + (size_t)t * D_ + base) = pk.q4;
    }
    gbar(a.bar + 4);

    // P5: ff1(l1)
    gemm_tile<64, 128, 1, 1, 1, 0, 1>(tile & 15, tile >> 4, 0, a.st,
                                      a.w1 + (size_t)4 * D_ * D_, a.b1 + 4 * D_,
                                      a.ff1, 2048, 2048, 512, nullptr, SMEM);
    gbar(a.bar + 5);

    // P6: ff2(l1) split-K x2
    { int r = tile & 255;
      gemm_tile<64, 64, 0, 0, 1, 0, 2>(r & 7, r >> 3, tile >> 8, a.ff1,
                                       a.w2 + (size_t)4 * D_ * D_, a.b2 + D_,
                                       a.tmpB, 2048, 512, 2048, nullptr, SMEM); }
    gbar(a.bar + 6);

    // P7: LN2(l1): st = bf16(LN(states + ff0 + ff1)*mask)
    {
        int t = (tile << 2) | wv;
        wave_ln(a.states + (size_t)t * D_, a.tmpB + (size_t)t * D_,
                a.tmpB + (size_t)2048 * D_ + (size_t)t * D_,
                a.n2g + D_, a.n2b + D_, a.mask[t],
                nullptr, a.st + (size_t)t * D_, lane);
    }
    gbar(a.bar + 7);

    // P8: kv projection -> kvbuf (aliases attnall; attn consumed in P4)
    gemm_tile<64, 64, 0, 0, 1, 0, 1>(tile & 15, tile >> 4, 0, a.st, a.kvw, a.kvb,
                                     a.attnall, 2048, 1024, 512, nullptr, SMEM);
    gbar(a.bar + 8);

    // P9: memory cross-attention (4 tokens/tile)
    mem_attn_tile(tile, a.qbuf, a.attnall, a.mask, a.memb, SMEM);
    gbar(a.bar + 9);

    // P10: t_ow projection + flags (64 tiles)
    if (tile < 64)
        gemm_tile<32, 64, 0, 1, 1, 1, 1>(tile & 7, tile >> 3, 0, a.memb, a.tow,
                                         a.tob, a.mem2, 256, 512, 512, a.flags, SMEM);
    gbar(a.bar + 10);

    // P11: final LLM projection -> out
    gemm_tile<32, 64, 0, 0, 1, 0, 1>(tile & 63, tile >> 6, 0, a.mem2, a.pw,
                                     a.projb, a.out, 256, 4096, 512, nullptr, SMEM);
}

// ---------------------------------------------------------------------------
// Merged proj + wfuse GEMM dispatch (32x64 tiles, 760 blocks), T3 dbuf.
// ---------------------------------------------------------------------------
__global__ __launch_bounds__(256) void projwfuse_kernel(
        const unsigned short* __restrict__ rel_bf, const unsigned short* __restrict__ rpw_bf,
        const float* __restrict__ rp_b, float* __restrict__ proj,
        const unsigned short* __restrict__ ow_bf, const unsigned short* __restrict__ vwT_bf,
        unsigned short* __restrict__ wfuse) {
    __shared__ __align__(16) unsigned short As[2 * 32 * 64];
    __shared__ __align__(16) unsigned short Bs[2 * 64 * 64];

    const unsigned short *A, *W;
    const float* bias;
    int Mg, Kg, bm, bn, obf;
    void* C;
    int t = blockIdx.x;
    if (t < 504) {
        A = rel_bf; W = rpw_bf; bias = rp_b; Mg = R_; Kg = RD_;
        C = proj; obf = 0; bn = (t & 7) * 64; bm = (t >> 3) * 32;
    } else {
        int u = t - 504, z = u >> 7, uu = u & 127;
        A = ow_bf + (size_t)z * 262144; W = vwT_bf + (size_t)z * 262144;
        bias = nullptr; Mg = 512; Kg = 512;
        C = wfuse + (size_t)z * 262144; obf = 1; bn = (uu & 7) * 64; bm = (uu >> 3) * 32;
    }

    const int tid = threadIdx.x;
    const int wave = tid >> 6, lane = tid & 63;
    const int quad = lane >> 4, l16 = lane & 15;
    const int wm = wave >> 1, wn = wave & 1;
    const int sub = lane >> 3;
    const int cpr = (lane & 7) ^ sub;

    f32x4 acc[2];
    acc[0] = (f32x4){0.f, 0.f, 0.f, 0.f};
    acc[1] = (f32x4){0.f, 0.f, 0.f, 0.f};

    auto stage = [&](int k0, int buf) {
        {
            int r0 = wave * 8;
            const unsigned short* g = A + (size_t)(bm + r0 + sub) * Kg + k0 + cpr * 8;
            __builtin_amdgcn_global_load_lds((GVoid*)g, (LVoid*)&As[buf * 32 * 64 + r0 * 64], 16, 0, 0);
        }
#pragma unroll
        for (int i = 0; i < 2; i++) {
            int r0 = (wave * 2 + i) * 8;
            const unsigned short* g = W + (size_t)(bn + r0 + sub) * Kg + k0 + cpr * 8;
            __builtin_amdgcn_global_load_lds((GVoid*)g, (LVoid*)&Bs[buf * 64 * 64 + r0 * 64], 16, 0, 0);
        }
    };

    const int nt = Kg / 64;
    stage(0, 0);
    __syncthreads();

    for (int tt = 0; tt < nt; tt++) {
        const int cur = tt & 1;
        if (tt + 1 < nt) stage((tt + 1) * 64, cur ^ 1);
#pragma unroll
        for (int h = 0; h < 2; h++) {
            bf16x8 af, bf[2];
            {
                int r = wm * 16 + l16;
                int ch = (h * 4 + quad) ^ (r & 7);
                af = *(const bf16x8*)&As[cur * 32 * 64 + r * 64 + ch * 8];
            }
#pragma unroll
            for (int j = 0; j < 2; j++) {
                int r = wn * 32 + j * 16 + l16;
                int ch = (h * 4 + quad) ^ (r & 7);
                bf[j] = *(const bf16x8*)&Bs[cur * 64 * 64 + r * 64 + ch * 8];
            }
#pragma unroll
            for (int j = 0; j < 2; j++)
                acc[j] = __builtin_amdgcn_mfma_f32_16x16x32_bf16(af, bf[j], acc[j], 0, 0, 0);
        }
        __syncthreads();
    }

#pragma unroll
    for (int j = 0; j < 2; j++) {
        int c = bn + wn * 32 + j * 16 + l16;
        float bv = bias ? bias[c] : 0.f;
#pragma unroll
        for (int reg = 0; reg < 4; reg++) {
            int r = bm + wm * 16 + quad * 4 + reg;
            if (r < Mg) {
                float v = acc[j][reg] + bv;
                if (obf)
                    ((unsigned short*)C)[(size_t)r * 512 + c] = f2bf(v);
                else
                    ((float*)C)[(size_t)r * 512 + c] = v;
            }
        }
    }
}

// ---------------------------------------------------------------------------
// prep_all: one launch for all input-only preprocessing.
// ---------------------------------------------------------------------------
struct PrepArgs {
    const float* src[9];
    unsigned short* dst[9];
    int cum4[10];
    int nb_cvt, total4;
    const float* ly_vw; unsigned short* vwT;
    const float* ly_ow; const float* ly_vb; const float* ly_ob; float* bfuse;
    const float* t_kb; const float* t_vb; float* kvb;
    const float* edge_mask; float* flags;
    const float* mem_q; const float* t_qw; const float* t_qb; float* qbuf;
};

__global__ __launch_bounds__(256) void prep_all(PrepArgs a) {
    int bx = blockIdx.x, tid = threadIdx.x;
    if (bx < a.nb_cvt) {
        int i = bx * 256 + tid;
        if (i < a.total4) {
            int k = 0;
#pragma unroll
            for (int j = 0; j < 8; j++) if (i >= a.cum4[j + 1]) k = j + 1;
            int o = i - a.cum4[k];
            float4 v = ((const float4*)a.src[k])[o];
            ushort4 u;
            u.x = f2bf(v.x); u.y = f2bf(v.y); u.z = f2bf(v.z); u.w = f2bf(v.w);
            ((ushort4*)a.dst[k])[o] = u;
        }
        return;
    }
    bx -= a.nb_cvt;
    if (bx < 512) {                            // vw transpose+convert
        __shared__ float tile[32][33];
        int l = bx >> 8, t16 = bx & 255;
        int j0 = (t16 >> 4) * 32, k0 = (t16 & 15) * 32;
        int tx = tid & 31, ty = tid >> 5;
        const float* src = a.ly_vw + (size_t)l * 512 * 512;
        for (int r = ty; r < 32; r += 8)
            tile[r][tx] = src[(size_t)(j0 + r) * 512 + k0 + tx];
        __syncthreads();
        unsigned short* dst = a.vwT + (size_t)l * 512 * 512;
        for (int r = ty; r < 32; r += 8)
            dst[(size_t)(k0 + r) * 512 + j0 + tx] = f2bf(tile[tx][r]);
        return;
    }
    bx -= 512;
    if (bx < 256) {                            // bfuse wave-dots
        int wid = bx * 4 + (tid >> 6);
        int z = wid >> 9, n = wid & 511, lane = tid & 63;
        const float* owr = a.ly_ow + (size_t)z * 512 * 512 + (size_t)n * 512;
        const float* vbr = a.ly_vb + (size_t)z * 512;
        float s = 0.f;
#pragma unroll
        for (int j = 0; j < 8; j++) s += owr[lane + 64 * j] * vbr[lane + 64 * j];
#pragma unroll
        for (int off = 32; off; off >>= 1) s += __shfl_xor(s, off, 64);
        if (lane == 0) a.bfuse[z * 512 + n] = s + a.ly_ob[z * 512 + n];
        return;
    }
    bx -= 256;
    if (bx < 1) {                              // kvb + flags
        __shared__ float red[4];
        for (int n = tid; n < 512; n += 256) {
            a.kvb[n] = a.t_kb[n];
            a.kvb[n + 512] = a.t_vb[n];
        }
        for (int b = 0; b < B_; b++) {
            float s = a.edge_mask[b * E_ + tid];
#pragma unroll
            for (int off = 32; off; off >>= 1) s += __shfl_xor(s, off, 64);
            if ((tid & 63) == 0) red[tid >> 6] = s;
            __syncthreads();
            if (tid == 0)
                a.flags[b] = (red[0] + red[1] + red[2] + red[3] == 0.f) ? 0.f : 1.f;
            __syncthreads();
        }
        return;
    }
    bx -= 1;
    {                                          // q-proj wave-dots
        int wid = bx * 4 + (tid >> 6);
        int m = wid >> 9, n = wid & 511, lane = tid & 63;
        const float* ar = a.mem_q + (size_t)m * 512;
        const float* br = a.t_qw + (size_t)n * 512;
        float s = 0.f;
#pragma unroll
        for (int j = 0; j < 8; j++) s += ar[lane + 64 * j] * br[lane + 64 * j];
#pragma unroll
        for (int off = 32; off; off >>= 1) s += __shfl_xor(s, off, 64);
        if (lane == 0) a.qbuf[(size_t)m * 512 + n] = s + a.t_qb[n];
    }
}

// Per-edge cosine sims -> wave-parallel top-8 -> mean agg.
__global__ void sim_topk_agg(const int* __restrict__ eids, const int* __restrict__ nids,
                             const float* __restrict__ proj,
                             unsigned short* __restrict__ agg_bf) {
    int be = blockIdx.x, tid = threadIdx.x;
    __shared__ float ev[512];
    __shared__ float sims[32];
    __shared__ int nid_s[32];
    __shared__ int sel[8];

    int eid = eids[be];
    const float* ep = proj + (size_t)eid * D_;
    ev[tid] = ep[tid];
    ev[tid + 256] = ep[tid + 256];
    if (tid < 32) nid_s[tid] = nids[be * N_ + tid];
    __syncthreads();

    int wid = tid >> 6, lane = tid & 63;
    float se = 0.f;
#pragma unroll
    for (int j = 0; j < 8; j++) { float v = ev[lane + 64 * j]; se += v * v; }
#pragma unroll
    for (int off = 32; off; off >>= 1) se += __shfl_xor(se, off, 64);
    float en = fmaxf(sqrtf(se), 1e-12f);

    for (int n = wid; n < N_; n += 4) {
        int nid = nid_s[n];
        const float* np = proj + (size_t)nid * D_;
        float s = 0.f, s2 = 0.f;
#pragma unroll
        for (int j = 0; j < 8; j++) {
            float v = np[lane + 64 * j];
            s += v * ev[lane + 64 * j];
            s2 += v * v;
        }
#pragma unroll
        for (int off = 32; off; off >>= 1) {
            s += __shfl_xor(s, off, 64);
            s2 += __shfl_xor(s2, off, 64);
        }
        if (lane == 0) sims[n] = s / (fmaxf(sqrtf(s2), 1e-12f) * en);
    }
    __syncthreads();

    if (tid < 64) {                            // wave-parallel top-8 (lax.top_k order)
        float v = (tid < 32) ? sims[tid] : -3.402823466e38f;
        int idx = tid;
        for (int k = 0; k < K_; k++) {
            float bv = v; int bi = idx;
#pragma unroll
            for (int off = 32; off; off >>= 1) {
                float ov = __shfl_xor(bv, off, 64);
                int oi = __shfl_xor(bi, off, 64);
                if (ov > bv || (ov == bv && oi < bi)) { bv = ov; bi = oi; }
            }
            if (tid == 0) sel[k] = nid_s[bi];
            if (idx == bi) v = -3.402823466e38f;
        }
    }
    __syncthreads();

    float a0 = 0.f, a1 = 0.f;
#pragma unroll
    for (int k = 0; k < K_; k++) {
        const float* sp = proj + (size_t)sel[k] * D_;
        a0 += sp[tid]; a1 += sp[tid + 256];
    }
    agg_bf[(size_t)be * D_ + tid] = f2bf(a0 * 0.125f);
    agg_bf[(size_t)be * D_ + tid + 256] = f2bf(a1 * 0.125f);
}

extern "C" void kernel_launch(void* const* d_in, const int* in_sizes, int n_in,
                              void* d_out, int out_size, void* d_ws, size_t ws_size,
                              hipStream_t stream) {
    const int*   edge_rel_ids     = (const int*)d_in[0];
    const int*   neighbor_rel_ids = (const int*)d_in[1];
    const float* edge_mask        = (const float*)d_in[2];
    const float* rel_emb          = (const float*)d_in[3];
    const float* rp_w             = (const float*)d_in[4];
    const float* rp_b             = (const float*)d_in[5];
    const float* ly_vw            = (const float*)d_in[6];
    const float* ly_vb            = (const float*)d_in[7];
    const float* ly_ow            = (const float*)d_in[8];
    const float* ly_ob            = (const float*)d_in[9];
    const float* ly_n1g           = (const float*)d_in[10];
    const float* ly_n1b           = (const float*)d_in[11];
    const float* ly_n2g           = (const float*)d_in[12];
    const float* ly_n2b           = (const float*)d_in[13];
    const float* ly_w1            = (const float*)d_in[14];
    const float* ly_b1            = (const float*)d_in[15];
    const float* ly_w2            = (const float*)d_in[16];
    const float* ly_b2            = (const float*)d_in[17];
    const float* mem_q            = (const float*)d_in[18];
    const float* t_qw             = (const float*)d_in[19];
    const float* t_qb             = (const float*)d_in[20];
    const float* t_kw             = (const float*)d_in[21];
    const float* t_kb             = (const float*)d_in[22];
    const float* t_vw             = (const float*)d_in[23];
    const float* t_vb             = (const float*)d_in[24];
    const float* t_ow             = (const float*)d_in[25];
    const float* t_ob             = (const float*)d_in[26];
    const float* proj_w           = (const float*)d_in[27];
    const float* proj_b           = (const float*)d_in[28];
    float* out = (float*)d_out;
    (void)ws_size; (void)in_sizes; (void)n_in; (void)out_size;

    char* ws = (char*)d_ws;
    size_t off = 0;
    auto allocf = [&](size_t n) { float* p = (float*)(ws + off); off += ((n * 4 + 255) & ~(size_t)255); return p; };
    auto allocb = [&](size_t n) { unsigned short* p = (unsigned short*)(ws + off); off += ((n * 2 + 255) & ~(size_t)255); return p; };

    const int T = B_ * E_;

    float* states  = allocf((size_t)T * D_);
    float* statesX = allocf((size_t)T * D_);
    float* proj    = allocf((size_t)R_ * D_);
    float* tmpB    = allocf((size_t)T * D_ * 2);
    float* attnall = allocf((size_t)T * 2 * D_);
    float* qbuf    = allocf((size_t)M_ * D_);
    float* bfuse   = allocf(2 * D_);
    float* kvb     = allocf(2 * D_);
    float* flags   = allocf(B_);
    int*   barrier = (int*)allocf(64);          // 16 counters, zeroed per launch

    unsigned short* rel_bf  = allocb((size_t)2048 * RD_);
    unsigned short* rpw_bf  = allocb((size_t)D_ * RD_);
    unsigned short* agg_bf  = allocb((size_t)T * D_);
    unsigned short* st_bf   = allocb((size_t)T * D_);
    unsigned short* ff1_bf  = allocb((size_t)T * 4 * D_);
    unsigned short* vwT_bf  = allocb((size_t)L_ * D_ * D_);
    unsigned short* ow_bf   = allocb((size_t)L_ * D_ * D_);
    unsigned short* wfuse   = allocb((size_t)L_ * D_ * D_);
    unsigned short* w1_bf   = allocb((size_t)L_ * 4 * D_ * D_);
    unsigned short* w2_bf   = allocb((size_t)L_ * 4 * D_ * D_);
    unsigned short* kvw_bf  = allocb((size_t)2 * D_ * D_);
    unsigned short* tow_bf  = allocb((size_t)D_ * D_);
    unsigned short* pw_bf   = allocb((size_t)HL_ * D_);
    unsigned short* memb_bf = allocb((size_t)B_ * M_ * D_);
    unsigned short* mem2_bf = allocb((size_t)B_ * M_ * D_);

    // ---- 0. zero the barrier counters (re-recorded each graph iteration) ----
    hipMemsetAsync(barrier, 0, 64 * sizeof(int), stream);

    // ---- 1. prep ----
    PrepArgs a;
    int sizes[9] = { R_ * RD_, D_ * RD_, L_ * D_ * D_, L_ * 4 * D_ * D_,
                     L_ * 4 * D_ * D_, D_ * D_, D_ * D_, D_ * D_, HL_ * D_ };
    const float* srcs[9] = { rel_emb, rp_w, ly_ow, ly_w1, ly_w2, t_kw, t_vw, t_ow, proj_w };
    unsigned short* dsts[9] = { rel_bf, rpw_bf, ow_bf, w1_bf, w2_bf,
                                kvw_bf, kvw_bf + (size_t)D_ * D_, tow_bf, pw_bf };
    int cum = 0;
    for (int i = 0; i < 9; i++) {
        a.src[i] = srcs[i]; a.dst[i] = dsts[i];
        a.cum4[i] = cum; cum += sizes[i] / 4;
    }
    a.cum4[9] = cum;
    a.total4 = cum;
    a.nb_cvt = (cum + 255) / 256;
    a.ly_vw = ly_vw; a.vwT = vwT_bf;
    a.ly_ow = ly_ow; a.ly_vb = ly_vb; a.ly_ob = ly_ob; a.bfuse = bfuse;
    a.t_kb = t_kb; a.t_vb = t_vb; a.kvb = kvb;
    a.edge_mask = edge_mask; a.flags = flags;
    a.mem_q = mem_q; a.t_qw = t_qw; a.t_qb = t_qb; a.qbuf = qbuf;
    int nblk = a.nb_cvt + 512 + 256 + 1 + 4096;
    prep_all<<<nblk, 256, 0, stream>>>(a);

    // ---- 2. proj + wfuse merged ----
    projwfuse_kernel<<<760, 256, 0, stream>>>(rel_bf, rpw_bf, rp_b, proj,
                                              ow_bf, vwT_bf, wfuse);

    // ---- 3. sims + top-k + aggregate ----
    sim_topk_agg<<<T, 256, 0, stream>>>(edge_rel_ids, neighbor_rel_ids, proj, agg_bf);

    // ---- 4. mega: steps 4..15, software grid barriers ----
    MegaArgs m;
    m.agg = agg_bf; m.wfuse = wfuse; m.w1 = w1_bf; m.w2 = w2_bf;
    m.kvw = kvw_bf; m.tow = tow_bf; m.pw = pw_bf;
    m.bfuse = bfuse; m.b1 = ly_b1; m.b2 = ly_b2;
    m.n1g = ly_n1g; m.n1b = ly_n1b; m.n2g = ly_n2g; m.n2b = ly_n2b;
    m.mask = edge_mask; m.kvb = kvb; m.qbuf = qbuf; m.tob = t_ob;
    m.projb = proj_b; m.flags = flags; m.proj = proj;
    m.eids = edge_rel_ids;
    m.attnall = attnall; m.statesX = statesX; m.states = states; m.tmpB = tmpB;
    m.st = st_bf; m.ff1 = ff1_bf; m.memb = memb_bf; m.mem2 = mem2_bf;
    m.out = out;
    m.bar = barrier;
    mega_kernel<<<NBLK, 256, 0, stream>>>(m);
}

// Round 8
// 296.593 us; speedup vs baseline: 3.5121x; 3.5121x over previous
//
#include <hip/hip_runtime.h>
#include <hip/hip_bf16.h>
#include <math.h>

#define B_   8
#define E_   256
#define N_   32
#define D_   512
#define RD_  768
#define R_   2000
#define L_   2
#define K_   8
#define M_   32
#define H_   8
#define DH_  64
#define HL_  4096
#define T_   2048

typedef float f32x4 __attribute__((ext_vector_type(4)));
typedef __bf16 bf16x8 __attribute__((ext_vector_type(8)));
typedef const __attribute__((address_space(1))) void GVoid;
typedef __attribute__((address_space(3))) void LVoid;

__device__ __forceinline__ float gelu_exact(float x) {
    return 0.5f * x * (1.0f + erff(x * 0.70710678118654752f));
}
__device__ __forceinline__ unsigned short f2bf(float x) {
    return __hip_bfloat16_raw(__float2bfloat16(x)).x;
}

// ---------------------------------------------------------------------------
// bf16 MFMA GEMM, T3-minimal double-buffered pipeline (R4):
//   STAGE(0); sync; for t { STAGE(t+1, other buf); COMPUTE(t); sync; }
// BK=64, global_load_lds width=16, XOR chunk-swizzle. Occupancy rule (R1/R8):
// grid >= 512 blocks; 4 blocks/CU preferred (TLP hides the barrier drain —
// m114; R7 showed in-kernel global barriers cost ~70us each, so the chain
// stays multi-dispatch). SPLITK>1: blockIdx.z picks K-range, f32 partial ->
// Cv + z*M*N, bias folded into partial z==0.
// ---------------------------------------------------------------------------
template <int TM, int TN, int ACT_GELU, int OUT_BF16, int HAS_BIAS, int FLAGS, int SPLITK = 1>
__global__ __launch_bounds__(256) void gemm_mfma(const unsigned short* __restrict__ A,
                                                 const unsigned short* __restrict__ W,
                                                 const float* __restrict__ bias,
                                                 void* __restrict__ Cv,
                                                 int M, int N, int K,
                                                 const float* __restrict__ rowflag) {
    constexpr int WTM = TM / 2, WTN = TN / 2;
    constexpr int RM = WTM / 16, RN = WTN / 16;
    constexpr int AI = TM / 32, BI = TN / 32;
    __shared__ __align__(16) unsigned short As[2 * TM * 64];
    __shared__ __align__(16) unsigned short Bs[2 * TN * 64];

    const int tid = threadIdx.x;
    const int wave = tid >> 6, lane = tid & 63;
    const int quad = lane >> 4, l16 = lane & 15;
    const int wm = wave >> 1, wn = wave & 1;
    const int bm = blockIdx.y * TM, bn = blockIdx.x * TN;
    const int bz = (SPLITK > 1) ? blockIdx.z : 0;
    const int sub = lane >> 3;
    const int cpr = (lane & 7) ^ sub;

    f32x4 acc[RM][RN];
#pragma unroll
    for (int i = 0; i < RM; i++)
#pragma unroll
        for (int j = 0; j < RN; j++) acc[i][j] = (f32x4){0.f, 0.f, 0.f, 0.f};

    const int kspan = K / SPLITK;
    const int kb = bz * kspan;
    const int nt = kspan / 64;

    auto stage = [&](int k0, int buf) {
#pragma unroll
        for (int i = 0; i < AI; i++) {
            int r0 = (wave * AI + i) * 8;
            const unsigned short* g = A + (size_t)(bm + r0 + sub) * K + k0 + cpr * 8;
            __builtin_amdgcn_global_load_lds((GVoid*)g, (LVoid*)&As[buf * TM * 64 + r0 * 64], 16, 0, 0);
        }
#pragma unroll
        for (int i = 0; i < BI; i++) {
            int r0 = (wave * BI + i) * 8;
            const unsigned short* g = W + (size_t)(bn + r0 + sub) * K + k0 + cpr * 8;
            __builtin_amdgcn_global_load_lds((GVoid*)g, (LVoid*)&Bs[buf * TN * 64 + r0 * 64], 16, 0, 0);
        }
    };

    stage(kb, 0);
    __syncthreads();                 // drains vmcnt(0): tile 0 resident

    for (int t = 0; t < nt; t++) {
        const int cur = t & 1;
        if (t + 1 < nt) stage(kb + (t + 1) * 64, cur ^ 1);
#pragma unroll
        for (int h = 0; h < 2; h++) {
            bf16x8 af[RM], bf[RN];
#pragma unroll
            for (int i = 0; i < RM; i++) {
                int r = wm * WTM + i * 16 + l16;
                int ch = (h * 4 + quad) ^ (r & 7);
                af[i] = *(const bf16x8*)&As[cur * TM * 64 + r * 64 + ch * 8];
            }
#pragma unroll
            for (int j = 0; j < RN; j++) {
                int r = wn * WTN + j * 16 + l16;
                int ch = (h * 4 + quad) ^ (r & 7);
                bf[j] = *(const bf16x8*)&Bs[cur * TN * 64 + r * 64 + ch * 8];
            }
#pragma unroll
            for (int i = 0; i < RM; i++)
#pragma unroll
                for (int j = 0; j < RN; j++)
                    acc[i][j] = __builtin_amdgcn_mfma_f32_16x16x32_bf16(af[i], bf[j], acc[i][j], 0, 0, 0);
        }
        __syncthreads();             // reads of cur done by all; prefetch drained
    }

    float* Cf = (float*)Cv + (size_t)bz * M * N;
#pragma unroll
    for (int i = 0; i < RM; i++) {
#pragma unroll
        for (int j = 0; j < RN; j++) {
            int c = bn + wn * WTN + j * 16 + l16;
            float bv = (HAS_BIAS && bz == 0) ? bias[c] : 0.f;
#pragma unroll
            for (int reg = 0; reg < 4; reg++) {
                int r = bm + wm * WTM + i * 16 + quad * 4 + reg;
                if (r < M) {
                    float v = acc[i][j][reg] + bv;
                    if (ACT_GELU) v = gelu_exact(v);
                    if (FLAGS) v *= rowflag[r >> 5];
                    if (OUT_BF16)
                        ((unsigned short*)Cv)[(size_t)r * N + c] = f2bf(v);
                    else
                        Cf[(size_t)r * N + c] = v;
                }
            }
        }
    }
}

// ---------------------------------------------------------------------------
// Merged proj + wfuse GEMM dispatch (32x64 tiles, 760 blocks), T3 dbuf.
// Tiles 0..503: proj = rel_emb_bf @ rp_w^T + rp_b (f32 out, M=2000 guard, K=768)
// Tiles 504..759: wfuse_z = ow_z @ vwT_z^T (bf16 out, K=512), z = 0,1
// ---------------------------------------------------------------------------
__global__ __launch_bounds__(256) void projwfuse_kernel(
        const unsigned short* __restrict__ rel_bf, const unsigned short* __restrict__ rpw_bf,
        const float* __restrict__ rp_b, float* __restrict__ proj,
        const unsigned short* __restrict__ ow_bf, const unsigned short* __restrict__ vwT_bf,
        unsigned short* __restrict__ wfuse) {
    __shared__ __align__(16) unsigned short As[2 * 32 * 64];
    __shared__ __align__(16) unsigned short Bs[2 * 64 * 64];

    const unsigned short *A, *W;
    const float* bias;
    int Mg, Kg, bm, bn, obf;
    void* C;
    int t = blockIdx.x;
    if (t < 504) {
        A = rel_bf; W = rpw_bf; bias = rp_b; Mg = R_; Kg = RD_;
        C = proj; obf = 0; bn = (t & 7) * 64; bm = (t >> 3) * 32;
    } else {
        int u = t - 504, z = u >> 7, uu = u & 127;
        A = ow_bf + (size_t)z * 262144; W = vwT_bf + (size_t)z * 262144;
        bias = nullptr; Mg = 512; Kg = 512;
        C = wfuse + (size_t)z * 262144; obf = 1; bn = (uu & 7) * 64; bm = (uu >> 3) * 32;
    }

    const int tid = threadIdx.x;
    const int wave = tid >> 6, lane = tid & 63;
    const int quad = lane >> 4, l16 = lane & 15;
    const int wm = wave >> 1, wn = wave & 1;
    const int sub = lane >> 3;
    const int cpr = (lane & 7) ^ sub;

    f32x4 acc[2];
    acc[0] = (f32x4){0.f, 0.f, 0.f, 0.f};
    acc[1] = (f32x4){0.f, 0.f, 0.f, 0.f};

    auto stage = [&](int k0, int buf) {
        {
            int r0 = wave * 8;
            const unsigned short* g = A + (size_t)(bm + r0 + sub) * Kg + k0 + cpr * 8;
            __builtin_amdgcn_global_load_lds((GVoid*)g, (LVoid*)&As[buf * 32 * 64 + r0 * 64], 16, 0, 0);
        }
#pragma unroll
        for (int i = 0; i < 2; i++) {
            int r0 = (wave * 2 + i) * 8;
            const unsigned short* g = W + (size_t)(bn + r0 + sub) * Kg + k0 + cpr * 8;
            __builtin_amdgcn_global_load_lds((GVoid*)g, (LVoid*)&Bs[buf * 64 * 64 + r0 * 64], 16, 0, 0);
        }
    };

    const int nt = Kg / 64;
    stage(0, 0);
    __syncthreads();

    for (int tt = 0; tt < nt; tt++) {
        const int cur = tt & 1;
        if (tt + 1 < nt) stage((tt + 1) * 64, cur ^ 1);
#pragma unroll
        for (int h = 0; h < 2; h++) {
            bf16x8 af, bf[2];
            {
                int r = wm * 16 + l16;
                int ch = (h * 4 + quad) ^ (r & 7);
                af = *(const bf16x8*)&As[cur * 32 * 64 + r * 64 + ch * 8];
            }
#pragma unroll
            for (int j = 0; j < 2; j++) {
                int r = wn * 32 + j * 16 + l16;
                int ch = (h * 4 + quad) ^ (r & 7);
                bf[j] = *(const bf16x8*)&Bs[cur * 64 * 64 + r * 64 + ch * 8];
            }
#pragma unroll
            for (int j = 0; j < 2; j++)
                acc[j] = __builtin_amdgcn_mfma_f32_16x16x32_bf16(af, bf[j], acc[j], 0, 0, 0);
        }
        __syncthreads();
    }

#pragma unroll
    for (int j = 0; j < 2; j++) {
        int c = bn + wn * 32 + j * 16 + l16;
        float bv = bias ? bias[c] : 0.f;
#pragma unroll
        for (int reg = 0; reg < 4; reg++) {
            int r = bm + wm * 16 + quad * 4 + reg;
            if (r < Mg) {
                float v = acc[j][reg] + bv;
                if (obf)
                    ((unsigned short*)C)[(size_t)r * 512 + c] = f2bf(v);
                else
                    ((float*)C)[(size_t)r * 512 + c] = v;
            }
        }
    }
}

// ---------------------------------------------------------------------------
// prep_all: one launch for all input-only preprocessing.
// ---------------------------------------------------------------------------
struct PrepArgs {
    const float* src[9];
    unsigned short* dst[9];
    int cum4[10];
    int nb_cvt, total4;
    const float* ly_vw; unsigned short* vwT;
    const float* ly_ow; const float* ly_vb; const float* ly_ob; float* bfuse;
    const float* t_kb; const float* t_vb; float* kvb;
    const float* edge_mask; float* flags;
    const float* mem_q; const float* t_qw; const float* t_qb; float* qbuf;
};

__global__ __launch_bounds__(256) void prep_all(PrepArgs a) {
    int bx = blockIdx.x, tid = threadIdx.x;
    if (bx < a.nb_cvt) {
        int i = bx * 256 + tid;
        if (i < a.total4) {
            int k = 0;
#pragma unroll
            for (int j = 0; j < 8; j++) if (i >= a.cum4[j + 1]) k = j + 1;
            int o = i - a.cum4[k];
            float4 v = ((const float4*)a.src[k])[o];
            ushort4 u;
            u.x = f2bf(v.x); u.y = f2bf(v.y); u.z = f2bf(v.z); u.w = f2bf(v.w);
            ((ushort4*)a.dst[k])[o] = u;
        }
        return;
    }
    bx -= a.nb_cvt;
    if (bx < 512) {                            // vw transpose+convert
        __shared__ float tile[32][33];
        int l = bx >> 8, t16 = bx & 255;
        int j0 = (t16 >> 4) * 32, k0 = (t16 & 15) * 32;
        int tx = tid & 31, ty = tid >> 5;
        const float* src = a.ly_vw + (size_t)l * 512 * 512;
        for (int r = ty; r < 32; r += 8)
            tile[r][tx] = src[(size_t)(j0 + r) * 512 + k0 + tx];
        __syncthreads();
        unsigned short* dst = a.vwT + (size_t)l * 512 * 512;
        for (int r = ty; r < 32; r += 8)
            dst[(size_t)(k0 + r) * 512 + j0 + tx] = f2bf(tile[tx][r]);
        return;
    }
    bx -= 512;
    if (bx < 256) {                            // bfuse wave-dots
        int wid = bx * 4 + (tid >> 6);
        int z = wid >> 9, n = wid & 511, lane = tid & 63;
        const float* owr = a.ly_ow + (size_t)z * 512 * 512 + (size_t)n * 512;
        const float* vbr = a.ly_vb + (size_t)z * 512;
        float s = 0.f;
#pragma unroll
        for (int j = 0; j < 8; j++) s += owr[lane + 64 * j] * vbr[lane + 64 * j];
#pragma unroll
        for (int off = 32; off; off >>= 1) s += __shfl_xor(s, off, 64);
        if (lane == 0) a.bfuse[z * 512 + n] = s + a.ly_ob[z * 512 + n];
        return;
    }
    bx -= 256;
    if (bx < 1) {                              // kvb + flags
        __shared__ float red[4];
        for (int n = tid; n < 512; n += 256) {
            a.kvb[n] = a.t_kb[n];
            a.kvb[n + 512] = a.t_vb[n];
        }
        for (int b = 0; b < B_; b++) {
            float s = a.edge_mask[b * E_ + tid];
#pragma unroll
            for (int off = 32; off; off >>= 1) s += __shfl_xor(s, off, 64);
            if ((tid & 63) == 0) red[tid >> 6] = s;
            __syncthreads();
            if (tid == 0)
                a.flags[b] = (red[0] + red[1] + red[2] + red[3] == 0.f) ? 0.f : 1.f;
            __syncthreads();
        }
        return;
    }
    bx -= 1;
    {                                          // q-proj wave-dots
        int wid = bx * 4 + (tid >> 6);
        int m = wid >> 9, n = wid & 511, lane = tid & 63;
        const float* ar = a.mem_q + (size_t)m * 512;
        const float* br = a.t_qw + (size_t)n * 512;
        float s = 0.f;
#pragma unroll
        for (int j = 0; j < 8; j++) s += ar[lane + 64 * j] * br[lane + 64 * j];
#pragma unroll
        for (int off = 32; off; off >>= 1) s += __shfl_xor(s, off, 64);
        if (lane == 0) a.qbuf[(size_t)m * 512 + n] = s + a.t_qb[n];
    }
}

// Per-edge cosine sims (norms inline) -> wave-parallel top-8 -> mean agg.
__global__ void sim_topk_agg(const int* __restrict__ eids, const int* __restrict__ nids,
                             const float* __restrict__ proj,
                             unsigned short* __restrict__ agg_bf, float* __restrict__ states) {
    int be = blockIdx.x, tid = threadIdx.x;
    __shared__ float ev[512];
    __shared__ float sims[32];
    __shared__ int nid_s[32];
    __shared__ int sel[8];

    int eid = eids[be];
    const float* ep = proj + (size_t)eid * D_;
    float e0 = ep[tid], e1 = ep[tid + 256];
    ev[tid] = e0; ev[tid + 256] = e1;
    states[(size_t)be * D_ + tid] = e0;
    states[(size_t)be * D_ + tid + 256] = e1;
    if (tid < 32) nid_s[tid] = nids[be * N_ + tid];
    __syncthreads();

    int wid = tid >> 6, lane = tid & 63;
    float se = 0.f;
#pragma unroll
    for (int j = 0; j < 8; j++) { float v = ev[lane + 64 * j]; se += v * v; }
#pragma unroll
    for (int off = 32; off; off >>= 1) se += __shfl_xor(se, off, 64);
    float en = fmaxf(sqrtf(se), 1e-12f);

    for (int n = wid; n < N_; n += 4) {
        int nid = nid_s[n];
        const float* np = proj + (size_t)nid * D_;
        float s = 0.f, s2 = 0.f;
#pragma unroll
        for (int j = 0; j < 8; j++) {
            float v = np[lane + 64 * j];
            s += v * ev[lane + 64 * j];
            s2 += v * v;
        }
#pragma unroll
        for (int off = 32; off; off >>= 1) {
            s += __shfl_xor(s, off, 64);
            s2 += __shfl_xor(s2, off, 64);
        }
        if (lane == 0) sims[n] = s / (fmaxf(sqrtf(s2), 1e-12f) * en);
    }
    __syncthreads();

    if (tid < 64) {                            // wave-parallel top-8 (lax.top_k order)
        float v = (tid < 32) ? sims[tid] : -3.402823466e38f;
        int idx = tid;
        for (int k = 0; k < K_; k++) {
            float bv = v; int bi = idx;
#pragma unroll
            for (int off = 32; off; off >>= 1) {
                float ov = __shfl_xor(bv, off, 64);
                int oi = __shfl_xor(bi, off, 64);
                if (ov > bv || (ov == bv && oi < bi)) { bv = ov; bi = oi; }
            }
            if (tid == 0) sel[k] = nid_s[bi];
            if (idx == bi) v = -3.402823466e38f;
        }
    }
    __syncthreads();

    float a0 = 0.f, a1 = 0.f;
#pragma unroll
    for (int k = 0; k < K_; k++) {
        const float* sp = proj + (size_t)sel[k] * D_;
        a0 += sp[tid]; a1 += sp[tid + 256];
    }
    agg_bf[(size_t)be * D_ + tid] = f2bf(a0 * 0.125f);
    agg_bf[(size_t)be * D_ + tid + 256] = f2bf(a1 * 0.125f);
}

// out = LN(x + y [+ extras])*g + b (optional *mask); y has row stride ystride,
// extras = nextra additional split-K partials at stride D_, T_*D_ apart.
// f32 out nullable (R5).
__global__ void add_ln_kernel(const float* __restrict__ x, const float* __restrict__ y,
                              int ystride, const float* __restrict__ extra, int nextra,
                              const float* __restrict__ g,
                              const float* __restrict__ bb, const float* __restrict__ mask,
                              float* __restrict__ out, unsigned short* __restrict__ out_bf) {
    int t = blockIdx.x, tid = threadIdx.x;
    const float* xr = x + (size_t)t * D_;
    const float* yr = y + (size_t)t * ystride;
    float x0 = xr[tid] + yr[tid];
    float x1 = xr[tid + 256] + yr[tid + 256];
    for (int j = 0; j < nextra; j++) {
        const float* er = extra + (size_t)j * T_ * D_ + (size_t)t * D_;
        x0 += er[tid];
        x1 += er[tid + 256];
    }
    __shared__ float red[8];
    float s = x0 + x1;
#pragma unroll
    for (int off = 32; off; off >>= 1) s += __shfl_xor(s, off, 64);
    int wid = tid >> 6;
    if ((tid & 63) == 0) red[wid] = s;
    __syncthreads();
    float mean = (red[0] + red[1] + red[2] + red[3]) * (1.f / 512.f);
    float d0 = x0 - mean, d1 = x1 - mean;
    float v = d0 * d0 + d1 * d1;
#pragma unroll
    for (int off = 32; off; off >>= 1) v += __shfl_xor(v, off, 64);
    if ((tid & 63) == 0) red[4 + wid] = v;
    __syncthreads();
    float var = (red[4] + red[5] + red[6] + red[7]) * (1.f / 512.f);
    float rs = rsqrtf(var + 1e-5f);
    float mv = mask ? mask[t] : 1.f;
    float o0 = (d0 * rs * g[tid] + bb[tid]) * mv;
    float o1 = (d1 * rs * g[tid + 256] + bb[tid + 256]) * mv;
    if (out) {
        out[(size_t)t * D_ + tid] = o0;
        out[(size_t)t * D_ + tid + 256] = o1;
    }
    out_bf[(size_t)t * D_ + tid] = f2bf(o0);
    out_bf[(size_t)t * D_ + tid + 256] = f2bf(o1);
}

// Double LN: s3 = LN( (LN(x+y[+extras])*g2+b2)*mask + att ) * g1 + b1.
__global__ void dbl_ln_kernel(const float* __restrict__ x, const float* __restrict__ y,
                              const float* __restrict__ extra, int nextra,
                              const float* __restrict__ g2, const float* __restrict__ b2,
                              const float* __restrict__ mask,
                              const float* __restrict__ att, int astride,
                              const float* __restrict__ g1, const float* __restrict__ b1,
                              float* __restrict__ out, unsigned short* __restrict__ out_bf) {
    int t = blockIdx.x, tid = threadIdx.x;
    const float* xr = x + (size_t)t * D_;
    const float* yr = y + (size_t)t * D_;
    float x0 = xr[tid] + yr[tid];
    float x1 = xr[tid + 256] + yr[tid + 256];
    for (int j = 0; j < nextra; j++) {
        const float* er = extra + (size_t)j * T_ * D_ + (size_t)t * D_;
        x0 += er[tid];
        x1 += er[tid + 256];
    }
    __shared__ float red[8];
    int wid = tid >> 6;
    // LN #1 (= LN2 of layer 0)
    float s = x0 + x1;
#pragma unroll
    for (int off = 32; off; off >>= 1) s += __shfl_xor(s, off, 64);
    if ((tid & 63) == 0) red[wid] = s;
    __syncthreads();
    float mean = (red[0] + red[1] + red[2] + red[3]) * (1.f / 512.f);
    float d0 = x0 - mean, d1 = x1 - mean;
    float v = d0 * d0 + d1 * d1;
#pragma unroll
    for (int off = 32; off; off >>= 1) v += __shfl_xor(v, off, 64);
    if ((tid & 63) == 0) red[4 + wid] = v;
    __syncthreads();
    float var = (red[4] + red[5] + red[6] + red[7]) * (1.f / 512.f);
    float rs = rsqrtf(var + 1e-5f);
    float mv = mask[t];
    float t0 = (d0 * rs * g2[tid] + b2[tid]) * mv;
    float t1 = (d1 * rs * g2[tid + 256] + b2[tid + 256]) * mv;
    // residual with layer-1 attention
    const float* ar = att + (size_t)t * astride;
    float y0 = t0 + ar[tid];
    float y1 = t1 + ar[tid + 256];
    __syncthreads();
    // LN #2 (= LN1 of layer 1)
    float s2 = y0 + y1;
#pragma unroll
    for (int off = 32; off; off >>= 1) s2 += __shfl_xor(s2, off, 64);
    if ((tid & 63) == 0) red[wid] = s2;
    __syncthreads();
    float mean2 = (red[0] + red[1] + red[2] + red[3]) * (1.f / 512.f);
    float e0 = y0 - mean2, e1 = y1 - mean2;
    float v2 = e0 * e0 + e1 * e1;
#pragma unroll
    for (int off = 32; off; off >>= 1) v2 += __shfl_xor(v2, off, 64);
    if ((tid & 63) == 0) red[4 + wid] = v2;
    __syncthreads();
    float var2 = (red[4] + red[5] + red[6] + red[7]) * (1.f / 512.f);
    float rs2 = rsqrtf(var2 + 1e-5f);
    float o0 = e0 * rs2 * g1[tid] + b1[tid];
    float o1 = e1 * rs2 * g1[tid + 256] + b1[tid + 256];
    out[(size_t)t * D_ + tid] = o0;
    out[(size_t)t * D_ + tid + 256] = o1;
    out_bf[(size_t)t * D_ + tid] = f2bf(o0);
    out_bf[(size_t)t * D_ + tid + 256] = f2bf(o1);
}

// Cross-attention over combined kv [T,1024]. R8: 8 memory tokens per block ->
// grid = B_*H_*(M_/8) = 256; K/V slabs read once per block (8x traffic cut vs
// original). Per-token accumulation order identical (absmax-stable).
__global__ void mem_attn(const float* __restrict__ qb, const float* __restrict__ kv,
                         const float* __restrict__ mask, unsigned short* __restrict__ memb) {
    int idx = blockIdx.x;
    int b = idx & 7;
    int h = (idx >> 3) & 7;
    int mg = idx >> 6;                 // 0..3 -> tokens mg*8 .. mg*8+7
    int tid = threadIdx.x;
    __shared__ float qh[8][64];
    __shared__ float sc[8][256];
    __shared__ float redm[4][8];
    __shared__ float reds[4][8];
    __shared__ float oacc[4][8][64];   // [part][m][d]

    for (int i = tid; i < 512; i += 256)
        qh[i >> 6][i & 63] = qb[(size_t)(mg * 8 + (i >> 6)) * D_ + h * DH_ + (i & 63)];
    float mk = mask[b * E_ + tid];
    __syncthreads();

    const float* kr = kv + ((size_t)(b * E_ + tid)) * 1024 + h * DH_;
    float s[8];
#pragma unroll
    for (int i = 0; i < 8; i++) s[i] = 0.f;
#pragma unroll
    for (int d = 0; d < DH_; d += 4) {
        float4 k4 = *(const float4*)(kr + d);
#pragma unroll
        for (int i = 0; i < 8; i++)
            s[i] += k4.x * qh[i][d] + k4.y * qh[i][d + 1] + k4.z * qh[i][d + 2] + k4.w * qh[i][d + 3];
    }
#pragma unroll
    for (int i = 0; i < 8; i++) {
        s[i] *= 0.125f;
        if (mk == 0.f) s[i] = -3.402823466e38f;
    }

    int wid = tid >> 6;
    float m[8];
#pragma unroll
    for (int i = 0; i < 8; i++) m[i] = s[i];
#pragma unroll
    for (int off = 32; off; off >>= 1)
#pragma unroll
        for (int i = 0; i < 8; i++) m[i] = fmaxf(m[i], __shfl_xor(m[i], off, 64));
    if ((tid & 63) == 0)
#pragma unroll
        for (int i = 0; i < 8; i++) redm[wid][i] = m[i];
    __syncthreads();
#pragma unroll
    for (int i = 0; i < 8; i++)
        m[i] = fmaxf(fmaxf(redm[0][i], redm[1][i]), fmaxf(redm[2][i], redm[3][i]));
    float p[8], u[8];
#pragma unroll
    for (int i = 0; i < 8; i++) { p[i] = expf(s[i] - m[i]); u[i] = p[i]; }
#pragma unroll
    for (int off = 32; off; off >>= 1)
#pragma unroll
        for (int i = 0; i < 8; i++) u[i] += __shfl_xor(u[i], off, 64);
    if ((tid & 63) == 0)
#pragma unroll
        for (int i = 0; i < 8; i++) reds[wid][i] = u[i];
    __syncthreads();
#pragma unroll
    for (int i = 0; i < 8; i++) {
        u[i] = reds[0][i] + reds[1][i] + reds[2][i] + reds[3][i];
        sc[i][tid] = p[i] / u[i];
    }
    __syncthreads();

    int d = tid & 63, part = tid >> 6;
    const float* vcol = kv + ((size_t)(b * E_ + part * 64)) * 1024 + 512 + h * DH_ + d;
    float acc[8];
#pragma unroll
    for (int i = 0; i < 8; i++) acc[i] = 0.f;
#pragma unroll 4
    for (int e = 0; e < 64; e++) {
        float vv = vcol[(size_t)e * 1024];
#pragma unroll
        for (int i = 0; i < 8; i++) acc[i] += sc[i][part * 64 + e] * vv;
    }
#pragma unroll
    for (int i = 0; i < 8; i++) oacc[part][i][d] = acc[i];
    __syncthreads();
    if (part == 0) {
#pragma unroll
        for (int i = 0; i < 8; i++)
            memb[((size_t)(b * M_ + mg * 8 + i)) * D_ + h * DH_ + d] =
                f2bf(oacc[0][i][d] + oacc[1][i][d] + oacc[2][i][d] + oacc[3][i][d]);
    }
}

extern "C" void kernel_launch(void* const* d_in, const int* in_sizes, int n_in,
                              void* d_out, int out_size, void* d_ws, size_t ws_size,
                              hipStream_t stream) {
    const int*   edge_rel_ids     = (const int*)d_in[0];
    const int*   neighbor_rel_ids = (const int*)d_in[1];
    const float* edge_mask        = (const float*)d_in[2];
    const float* rel_emb          = (const float*)d_in[3];
    const float* rp_w             = (const float*)d_in[4];
    const float* rp_b             = (const float*)d_in[5];
    const float* ly_vw            = (const float*)d_in[6];
    const float* ly_vb            = (const float*)d_in[7];
    const float* ly_ow            = (const float*)d_in[8];
    const float* ly_ob            = (const float*)d_in[9];
    const float* ly_n1g           = (const float*)d_in[10];
    const float* ly_n1b           = (const float*)d_in[11];
    const float* ly_n2g           = (const float*)d_in[12];
    const float* ly_n2b           = (const float*)d_in[13];
    const float* ly_w1            = (const float*)d_in[14];
    const float* ly_b1            = (const float*)d_in[15];
    const float* ly_w2            = (const float*)d_in[16];
    const float* ly_b2            = (const float*)d_in[17];
    const float* mem_q            = (const float*)d_in[18];
    const float* t_qw             = (const float*)d_in[19];
    const float* t_qb             = (const float*)d_in[20];
    const float* t_kw             = (const float*)d_in[21];
    const float* t_kb             = (const float*)d_in[22];
    const float* t_vw             = (const float*)d_in[23];
    const float* t_vb             = (const float*)d_in[24];
    const float* t_ow             = (const float*)d_in[25];
    const float* t_ob             = (const float*)d_in[26];
    const float* proj_w           = (const float*)d_in[27];
    const float* proj_b           = (const float*)d_in[28];
    float* out = (float*)d_out;
    (void)ws_size; (void)in_sizes; (void)n_in; (void)out_size;

    char* ws = (char*)d_ws;
    size_t off = 0;
    auto allocf = [&](size_t n) { float* p = (float*)(ws + off); off += ((n * 4 + 255) & ~(size_t)255); return p; };
    auto allocb = [&](size_t n) { unsigned short* p = (unsigned short*)(ws + off); off += ((n * 2 + 255) & ~(size_t)255); return p; };

    const int T = B_ * E_;

    float* states  = allocf((size_t)T * D_);   // states0, later states3
    float* statesX = allocf((size_t)T * D_);   // states1, later states4
    float* proj    = allocf((size_t)R_ * D_);
    float* tmpB    = allocf((size_t)T * D_ * 4);  // 4 split-K partials
    float* attnall = allocf((size_t)T * 2 * D_);
    float* qbuf    = allocf((size_t)M_ * D_);
    float* bfuse   = allocf(2 * D_);
    float* kvb     = allocf(2 * D_);
    float* flags   = allocf(B_);
    float* kvbuf   = attnall;   // alias: attnall dead after dbl_ln consumed l1 slice

    unsigned short* rel_bf  = allocb((size_t)2048 * RD_);   // rows padded to 2048
    unsigned short* rpw_bf  = allocb((size_t)D_ * RD_);
    unsigned short* agg_bf  = allocb((size_t)T * D_);
    unsigned short* st_bf   = allocb((size_t)T * D_);
    unsigned short* ff1_bf  = allocb((size_t)T * 4 * D_);
    unsigned short* vwT_bf  = allocb((size_t)L_ * D_ * D_);
    unsigned short* ow_bf   = allocb((size_t)L_ * D_ * D_);
    unsigned short* wfuse   = allocb((size_t)L_ * D_ * D_);
    unsigned short* w1_bf   = allocb((size_t)L_ * 4 * D_ * D_);
    unsigned short* w2_bf   = allocb((size_t)L_ * 4 * D_ * D_);
    unsigned short* kvw_bf  = allocb((size_t)2 * D_ * D_);
    unsigned short* tow_bf  = allocb((size_t)D_ * D_);
    unsigned short* pw_bf   = allocb((size_t)HL_ * D_);
    unsigned short* memb_bf = allocb((size_t)B_ * M_ * D_);
    unsigned short* mem2_bf = allocb((size_t)B_ * M_ * D_);

    // ---- 1. prep ----
    PrepArgs a;
    int sizes[9] = { R_ * RD_, D_ * RD_, L_ * D_ * D_, L_ * 4 * D_ * D_,
                     L_ * 4 * D_ * D_, D_ * D_, D_ * D_, D_ * D_, HL_ * D_ };
    const float* srcs[9] = { rel_emb, rp_w, ly_ow, ly_w1, ly_w2, t_kw, t_vw, t_ow, proj_w };
    unsigned short* dsts[9] = { rel_bf, rpw_bf, ow_bf, w1_bf, w2_bf,
                                kvw_bf, kvw_bf + (size_t)D_ * D_, tow_bf, pw_bf };
    int cum = 0;
    for (int i = 0; i < 9; i++) {
        a.src[i] = srcs[i]; a.dst[i] = dsts[i];
        a.cum4[i] = cum; cum += sizes[i] / 4;
    }
    a.cum4[9] = cum;
    a.total4 = cum;
    a.nb_cvt = (cum + 255) / 256;
    a.ly_vw = ly_vw; a.vwT = vwT_bf;
    a.ly_ow = ly_ow; a.ly_vb = ly_vb; a.ly_ob = ly_ob; a.bfuse = bfuse;
    a.t_kb = t_kb; a.t_vb = t_vb; a.kvb = kvb;
    a.edge_mask = edge_mask; a.flags = flags;
    a.mem_q = mem_q; a.t_qw = t_qw; a.t_qb = t_qb; a.qbuf = qbuf;
    int nblk = a.nb_cvt + 512 + 256 + 1 + 4096;
    prep_all<<<nblk, 256, 0, stream>>>(a);

    // ---- 2. proj + wfuse merged ----
    projwfuse_kernel<<<760, 256, 0, stream>>>(rel_bf, rpw_bf, rp_b, proj,
                                              ow_bf, vwT_bf, wfuse);

    // ---- 3. sims + top-k + aggregate + states0 init ----
    sim_topk_agg<<<T, 256, 0, stream>>>(edge_rel_ids, neighbor_rel_ids, proj,
                                        agg_bf, states);

    // ---- 4. attn (both layers) = agg @ wfuse^T + bfuse  [2048,1024] ----
    gemm_mfma<64, 64, 0, 0, 1, 0><<<dim3(16, 32), 256, 0, stream>>>(
        agg_bf, wfuse, bfuse, attnall, T, 2 * D_, D_, nullptr);

    // ---- 5. LN1(l0): states1 = LN(states0 + attnall_l0) ----
    add_ln_kernel<<<T, 256, 0, stream>>>(states, attnall, 2 * D_, nullptr, 0,
                                         ly_n1g, ly_n1b, nullptr, statesX, st_bf);
    // ---- 6. ff1(l0), 64x64 @ 1024 blocks (4/CU) ----
    gemm_mfma<64, 64, 1, 1, 1, 0><<<dim3(32, 32), 256, 0, stream>>>(
        st_bf, w1_bf, ly_b1, ff1_bf, T, 4 * D_, D_, nullptr);
    // ---- 7. ff2(l0), 64x64 split-K x4: 1024 blocks (4/CU) ----
    gemm_mfma<64, 64, 0, 0, 1, 0, 4><<<dim3(8, 32, 4), 256, 0, stream>>>(
        ff1_bf, w2_bf, ly_b2, tmpB, T, D_, 4 * D_, nullptr);
    // ---- 8. LN2(l0)+LN1(l1) fused ----
    dbl_ln_kernel<<<T, 256, 0, stream>>>(statesX, tmpB, tmpB + (size_t)T * D_, 3,
                                         ly_n2g, ly_n2b, edge_mask,
                                         attnall + D_, 2 * D_, ly_n1g + D_, ly_n1b + D_,
                                         states, st_bf);
    // ---- 9. ff1(l1), 64x64 @ 1024 blocks ----
    gemm_mfma<64, 64, 1, 1, 1, 0><<<dim3(32, 32), 256, 0, stream>>>(
        st_bf, w1_bf + (size_t)4 * D_ * D_, ly_b1 + 4 * D_, ff1_bf, T, 4 * D_, D_, nullptr);
    // ---- 10. ff2(l1), 64x64 split-K x4 ----
    gemm_mfma<64, 64, 0, 0, 1, 0, 4><<<dim3(8, 32, 4), 256, 0, stream>>>(
        ff1_bf, w2_bf + (size_t)4 * D_ * D_, ly_b2 + D_, tmpB, T, D_, 4 * D_, nullptr);
    // ---- 11. LN2(l1): states4 = LN(states3 + sum(ff partials))*mask ----
    add_ln_kernel<<<T, 256, 0, stream>>>(states, tmpB, D_, tmpB + (size_t)T * D_, 3,
                                         ly_n2g + D_, ly_n2b + D_, edge_mask,
                                         nullptr, st_bf);
    // ---- 12. kv projection [2048,1024] ----
    gemm_mfma<64, 64, 0, 0, 1, 0><<<dim3(16, 32), 256, 0, stream>>>(
        st_bf, kvw_bf, kvb, kvbuf, T, 2 * D_, D_, nullptr);
    // ---- 13. memory cross-attention, 8 tokens/block (256 blocks) ----
    mem_attn<<<B_ * H_ * (M_ / 8), 256, 0, stream>>>(qbuf, kvbuf, edge_mask, memb_bf);
    // ---- 14. t_ow projection + no-edge zeroing via flags ----
    gemm_mfma<32, 64, 0, 1, 1, 1><<<dim3(8, 8), 256, 0, stream>>>(
        memb_bf, tow_bf, t_ob, mem2_bf, B_ * M_, D_, D_, flags);
    // ---- 15. final LLM projection ----
    gemm_mfma<32, 64, 0, 0, 1, 0><<<dim3(64, 8), 256, 0, stream>>>(
        mem2_bf, pw_bf, proj_b, out, B_ * M_, HL_, D_, nullptr);
}

// Round 9
// 292.798 us; speedup vs baseline: 3.5576x; 1.0130x over previous
//
#include <hip/hip_runtime.h>
#include <hip/hip_bf16.h>
#include <math.h>

#define B_   8
#define E_   256
#define N_   32
#define D_   512
#define RD_  768
#define R_   2000
#define L_   2
#define K_   8
#define M_   32
#define H_   8
#define DH_  64
#define HL_  4096

typedef float f32x4 __attribute__((ext_vector_type(4)));
typedef __bf16 bf16x8 __attribute__((ext_vector_type(8)));
typedef const __attribute__((address_space(1))) void GVoid;
typedef __attribute__((address_space(3))) void LVoid;

__device__ __forceinline__ float gelu_exact(float x) {
    return 0.5f * x * (1.0f + erff(x * 0.70710678118654752f));
}
__device__ __forceinline__ unsigned short f2bf(float x) {
    return __hip_bfloat16_raw(__float2bfloat16(x)).x;
}

// ---------------------------------------------------------------------------
// bf16 MFMA GEMM, T3-minimal double-buffered pipeline (R4/R5-proven):
//   STAGE(0); sync; for t { STAGE(t+1, other buf); COMPUTE(t); sync; }
// BK=64, global_load_lds width=16, XOR chunk-swizzle.
// Config locked per R1/R8 sweeps: grid >= 512 blocks (2/CU); bigger tiles,
// split-K>2, 4/CU variants all neutral-or-worse at this problem scale.
// R7 lesson: in-kernel grid barriers cost ~70us each (per-block L2 flush on
// 8 XCDs) -> the chain stays multi-dispatch; launch boundary IS the barrier.
// ---------------------------------------------------------------------------
template <int TM, int TN, int ACT_GELU, int OUT_BF16, int HAS_BIAS, int FLAGS, int SPLITK = 1>
__global__ __launch_bounds__(256) void gemm_mfma(const unsigned short* __restrict__ A,
                                                 const unsigned short* __restrict__ W,
                                                 const float* __restrict__ bias,
                                                 void* __restrict__ Cv,
                                                 int M, int N, int K,
                                                 const float* __restrict__ rowflag) {
    constexpr int WTM = TM / 2, WTN = TN / 2;
    constexpr int RM = WTM / 16, RN = WTN / 16;
    constexpr int AI = TM / 32, BI = TN / 32;
    __shared__ __align__(16) unsigned short As[2 * TM * 64];
    __shared__ __align__(16) unsigned short Bs[2 * TN * 64];

    const int tid = threadIdx.x;
    const int wave = tid >> 6, lane = tid & 63;
    const int quad = lane >> 4, l16 = lane & 15;
    const int wm = wave >> 1, wn = wave & 1;
    const int bm = blockIdx.y * TM, bn = blockIdx.x * TN;
    const int bz = (SPLITK > 1) ? blockIdx.z : 0;
    const int sub = lane >> 3;
    const int cpr = (lane & 7) ^ sub;

    f32x4 acc[RM][RN];
#pragma unroll
    for (int i = 0; i < RM; i++)
#pragma unroll
        for (int j = 0; j < RN; j++) acc[i][j] = (f32x4){0.f, 0.f, 0.f, 0.f};

    const int kspan = K / SPLITK;
    const int kb = bz * kspan;
    const int nt = kspan / 64;

    auto stage = [&](int k0, int buf) {
#pragma unroll
        for (int i = 0; i < AI; i++) {
            int r0 = (wave * AI + i) * 8;
            const unsigned short* g = A + (size_t)(bm + r0 + sub) * K + k0 + cpr * 8;
            __builtin_amdgcn_global_load_lds((GVoid*)g, (LVoid*)&As[buf * TM * 64 + r0 * 64], 16, 0, 0);
        }
#pragma unroll
        for (int i = 0; i < BI; i++) {
            int r0 = (wave * BI + i) * 8;
            const unsigned short* g = W + (size_t)(bn + r0 + sub) * K + k0 + cpr * 8;
            __builtin_amdgcn_global_load_lds((GVoid*)g, (LVoid*)&Bs[buf * TN * 64 + r0 * 64], 16, 0, 0);
        }
    };

    stage(kb, 0);
    __syncthreads();                 // drains vmcnt(0): tile 0 resident

    for (int t = 0; t < nt; t++) {
        const int cur = t & 1;
        if (t + 1 < nt) stage(kb + (t + 1) * 64, cur ^ 1);
#pragma unroll
        for (int h = 0; h < 2; h++) {
            bf16x8 af[RM], bf[RN];
#pragma unroll
            for (int i = 0; i < RM; i++) {
                int r = wm * WTM + i * 16 + l16;
                int ch = (h * 4 + quad) ^ (r & 7);
                af[i] = *(const bf16x8*)&As[cur * TM * 64 + r * 64 + ch * 8];
            }
#pragma unroll
            for (int j = 0; j < RN; j++) {
                int r = wn * WTN + j * 16 + l16;
                int ch = (h * 4 + quad) ^ (r & 7);
                bf[j] = *(const bf16x8*)&Bs[cur * TN * 64 + r * 64 + ch * 8];
            }
#pragma unroll
            for (int i = 0; i < RM; i++)
#pragma unroll
                for (int j = 0; j < RN; j++)
                    acc[i][j] = __builtin_amdgcn_mfma_f32_16x16x32_bf16(af[i], bf[j], acc[i][j], 0, 0, 0);
        }
        __syncthreads();             // reads of cur done by all; prefetch drained
    }

    float* Cf = (float*)Cv + (size_t)bz * M * N;
#pragma unroll
    for (int i = 0; i < RM; i++) {
#pragma unroll
        for (int j = 0; j < RN; j++) {
            int c = bn + wn * WTN + j * 16 + l16;
            float bv = (HAS_BIAS && bz == 0) ? bias[c] : 0.f;
#pragma unroll
            for (int reg = 0; reg < 4; reg++) {
                int r = bm + wm * WTM + i * 16 + quad * 4 + reg;
                if (r < M) {
                    float v = acc[i][j][reg] + bv;
                    if (ACT_GELU) v = gelu_exact(v);
                    if (FLAGS) v *= rowflag[r >> 5];
                    if (OUT_BF16)
                        ((unsigned short*)Cv)[(size_t)r * N + c] = f2bf(v);
                    else
                        Cf[(size_t)r * N + c] = v;
                }
            }
        }
    }
}

// ---------------------------------------------------------------------------
// Merged proj + wfuse GEMM dispatch (32x64 tiles, 760 blocks), T3 dbuf.
// Tiles 0..503: proj = rel_emb_bf @ rp_w^T + rp_b (f32 out, M=2000 guard, K=768)
// Tiles 504..759: wfuse_z = ow_z @ vwT_z^T (bf16 out, K=512), z = 0,1
// ---------------------------------------------------------------------------
__global__ __launch_bounds__(256) void projwfuse_kernel(
        const unsigned short* __restrict__ rel_bf, const unsigned short* __restrict__ rpw_bf,
        const float* __restrict__ rp_b, float* __restrict__ proj,
        const unsigned short* __restrict__ ow_bf, const unsigned short* __restrict__ vwT_bf,
        unsigned short* __restrict__ wfuse) {
    __shared__ __align__(16) unsigned short As[2 * 32 * 64];
    __shared__ __align__(16) unsigned short Bs[2 * 64 * 64];

    const unsigned short *A, *W;
    const float* bias;
    int Mg, Kg, bm, bn, obf;
    void* C;
    int t = blockIdx.x;
    if (t < 504) {
        A = rel_bf; W = rpw_bf; bias = rp_b; Mg = R_; Kg = RD_;
        C = proj; obf = 0; bn = (t & 7) * 64; bm = (t >> 3) * 32;
    } else {
        int u = t - 504, z = u >> 7, uu = u & 127;
        A = ow_bf + (size_t)z * 262144; W = vwT_bf + (size_t)z * 262144;
        bias = nullptr; Mg = 512; Kg = 512;
        C = wfuse + (size_t)z * 262144; obf = 1; bn = (uu & 7) * 64; bm = (uu >> 3) * 32;
    }

    const int tid = threadIdx.x;
    const int wave = tid >> 6, lane = tid & 63;
    const int quad = lane >> 4, l16 = lane & 15;
    const int wm = wave >> 1, wn = wave & 1;
    const int sub = lane >> 3;
    const int cpr = (lane & 7) ^ sub;

    f32x4 acc[2];
    acc[0] = (f32x4){0.f, 0.f, 0.f, 0.f};
    acc[1] = (f32x4){0.f, 0.f, 0.f, 0.f};

    auto stage = [&](int k0, int buf) {
        {
            int r0 = wave * 8;
            const unsigned short* g = A + (size_t)(bm + r0 + sub) * Kg + k0 + cpr * 8;
            __builtin_amdgcn_global_load_lds((GVoid*)g, (LVoid*)&As[buf * 32 * 64 + r0 * 64], 16, 0, 0);
        }
#pragma unroll
        for (int i = 0; i < 2; i++) {
            int r0 = (wave * 2 + i) * 8;
            const unsigned short* g = W + (size_t)(bn + r0 + sub) * Kg + k0 + cpr * 8;
            __builtin_amdgcn_global_load_lds((GVoid*)g, (LVoid*)&Bs[buf * 64 * 64 + r0 * 64], 16, 0, 0);
        }
    };

    const int nt = Kg / 64;
    stage(0, 0);
    __syncthreads();

    for (int tt = 0; tt < nt; tt++) {
        const int cur = tt & 1;
        if (tt + 1 < nt) stage((tt + 1) * 64, cur ^ 1);
#pragma unroll
        for (int h = 0; h < 2; h++) {
            bf16x8 af, bf[2];
            {
                int r = wm * 16 + l16;
                int ch = (h * 4 + quad) ^ (r & 7);
                af = *(const bf16x8*)&As[cur * 32 * 64 + r * 64 + ch * 8];
            }
#pragma unroll
            for (int j = 0; j < 2; j++) {
                int r = wn * 32 + j * 16 + l16;
                int ch = (h * 4 + quad) ^ (r & 7);
                bf[j] = *(const bf16x8*)&Bs[cur * 64 * 64 + r * 64 + ch * 8];
            }
#pragma unroll
            for (int j = 0; j < 2; j++)
                acc[j] = __builtin_amdgcn_mfma_f32_16x16x32_bf16(af, bf[j], acc[j], 0, 0, 0);
        }
        __syncthreads();
    }

#pragma unroll
    for (int j = 0; j < 2; j++) {
        int c = bn + wn * 32 + j * 16 + l16;
        float bv = bias ? bias[c] : 0.f;
#pragma unroll
        for (int reg = 0; reg < 4; reg++) {
            int r = bm + wm * 16 + quad * 4 + reg;
            if (r < Mg) {
                float v = acc[j][reg] + bv;
                if (obf)
                    ((unsigned short*)C)[(size_t)r * 512 + c] = f2bf(v);
                else
                    ((float*)C)[(size_t)r * 512 + c] = v;
            }
        }
    }
}

// ---------------------------------------------------------------------------
// prep_all: one launch for all input-only preprocessing.
// ---------------------------------------------------------------------------
struct PrepArgs {
    const float* src[9];
    unsigned short* dst[9];
    int cum4[10];
    int nb_cvt, total4;
    const float* ly_vw; unsigned short* vwT;
    const float* ly_ow; const float* ly_vb; const float* ly_ob; float* bfuse;
    const float* t_kb; const float* t_vb; float* kvb;
    const float* edge_mask; float* flags;
    const float* mem_q; const float* t_qw; const float* t_qb; float* qbuf;
};

__global__ __launch_bounds__(256) void prep_all(PrepArgs a) {
    int bx = blockIdx.x, tid = threadIdx.x;
    if (bx < a.nb_cvt) {
        int i = bx * 256 + tid;
        if (i < a.total4) {
            int k = 0;
#pragma unroll
            for (int j = 0; j < 8; j++) if (i >= a.cum4[j + 1]) k = j + 1;
            int o = i - a.cum4[k];
            float4 v = ((const float4*)a.src[k])[o];
            ushort4 u;
            u.x = f2bf(v.x); u.y = f2bf(v.y); u.z = f2bf(v.z); u.w = f2bf(v.w);
            ((ushort4*)a.dst[k])[o] = u;
        }
        return;
    }
    bx -= a.nb_cvt;
    if (bx < 512) {                            // vw transpose+convert
        __shared__ float tile[32][33];
        int l = bx >> 8, t16 = bx & 255;
        int j0 = (t16 >> 4) * 32, k0 = (t16 & 15) * 32;
        int tx = tid & 31, ty = tid >> 5;
        const float* src = a.ly_vw + (size_t)l * 512 * 512;
        for (int r = ty; r < 32; r += 8)
            tile[r][tx] = src[(size_t)(j0 + r) * 512 + k0 + tx];
        __syncthreads();
        unsigned short* dst = a.vwT + (size_t)l * 512 * 512;
        for (int r = ty; r < 32; r += 8)
            dst[(size_t)(k0 + r) * 512 + j0 + tx] = f2bf(tile[tx][r]);
        return;
    }
    bx -= 512;
    if (bx < 256) {                            // bfuse wave-dots
        int wid = bx * 4 + (tid >> 6);
        int z = wid >> 9, n = wid & 511, lane = tid & 63;
        const float* owr = a.ly_ow + (size_t)z * 512 * 512 + (size_t)n * 512;
        const float* vbr = a.ly_vb + (size_t)z * 512;
        float s = 0.f;
#pragma unroll
        for (int j = 0; j < 8; j++) s += owr[lane + 64 * j] * vbr[lane + 64 * j];
#pragma unroll
        for (int off = 32; off; off >>= 1) s += __shfl_xor(s, off, 64);
        if (lane == 0) a.bfuse[z * 512 + n] = s + a.ly_ob[z * 512 + n];
        return;
    }
    bx -= 256;
    if (bx < 1) {                              // kvb + flags
        __shared__ float red[4];
        for (int n = tid; n < 512; n += 256) {
            a.kvb[n] = a.t_kb[n];
            a.kvb[n + 512] = a.t_vb[n];
        }
        for (int b = 0; b < B_; b++) {
            float s = a.edge_mask[b * E_ + tid];
#pragma unroll
            for (int off = 32; off; off >>= 1) s += __shfl_xor(s, off, 64);
            if ((tid & 63) == 0) red[tid >> 6] = s;
            __syncthreads();
            if (tid == 0)
                a.flags[b] = (red[0] + red[1] + red[2] + red[3] == 0.f) ? 0.f : 1.f;
            __syncthreads();
        }
        return;
    }
    bx -= 1;
    {                                          // q-proj wave-dots
        int wid = bx * 4 + (tid >> 6);
        int m = wid >> 9, n = wid & 511, lane = tid & 63;
        const float* ar = a.mem_q + (size_t)m * 512;
        const float* br = a.t_qw + (size_t)n * 512;
        float s = 0.f;
#pragma unroll
        for (int j = 0; j < 8; j++) s += ar[lane + 64 * j] * br[lane + 64 * j];
#pragma unroll
        for (int off = 32; off; off >>= 1) s += __shfl_xor(s, off, 64);
        if (lane == 0) a.qbuf[(size_t)m * 512 + n] = s + a.t_qb[n];
    }
}

// Per-edge cosine sims (norms inline) -> wave-parallel top-8 -> mean agg.
// R9: no states0 write — LN1 gathers proj[eids[t]] directly.
__global__ void sim_topk_agg(const int* __restrict__ eids, const int* __restrict__ nids,
                             const float* __restrict__ proj,
                             unsigned short* __restrict__ agg_bf) {
    int be = blockIdx.x, tid = threadIdx.x;
    __shared__ float ev[512];
    __shared__ float sims[32];
    __shared__ int nid_s[32];
    __shared__ int sel[8];

    int eid = eids[be];
    const float* ep = proj + (size_t)eid * D_;
    ev[tid] = ep[tid];
    ev[tid + 256] = ep[tid + 256];
    if (tid < 32) nid_s[tid] = nids[be * N_ + tid];
    __syncthreads();

    int wid = tid >> 6, lane = tid & 63;
    float se = 0.f;
#pragma unroll
    for (int j = 0; j < 8; j++) { float v = ev[lane + 64 * j]; se += v * v; }
#pragma unroll
    for (int off = 32; off; off >>= 1) se += __shfl_xor(se, off, 64);
    float en = fmaxf(sqrtf(se), 1e-12f);

    for (int n = wid; n < N_; n += 4) {
        int nid = nid_s[n];
        const float* np = proj + (size_t)nid * D_;
        float s = 0.f, s2 = 0.f;
#pragma unroll
        for (int j = 0; j < 8; j++) {
            float v = np[lane + 64 * j];
            s += v * ev[lane + 64 * j];
            s2 += v * v;
        }
#pragma unroll
        for (int off = 32; off; off >>= 1) {
            s += __shfl_xor(s, off, 64);
            s2 += __shfl_xor(s2, off, 64);
        }
        if (lane == 0) sims[n] = s / (fmaxf(sqrtf(s2), 1e-12f) * en);
    }
    __syncthreads();

    if (tid < 64) {                            // wave-parallel top-8 (lax.top_k order)
        float v = (tid < 32) ? sims[tid] : -3.402823466e38f;
        int idx = tid;
        for (int k = 0; k < K_; k++) {
            float bv = v; int bi = idx;
#pragma unroll
            for (int off = 32; off; off >>= 1) {
                float ov = __shfl_xor(bv, off, 64);
                int oi = __shfl_xor(bi, off, 64);
                if (ov > bv || (ov == bv && oi < bi)) { bv = ov; bi = oi; }
            }
            if (tid == 0) sel[k] = nid_s[bi];
            if (idx == bi) v = -3.402823466e38f;
        }
    }
    __syncthreads();

    float a0 = 0.f, a1 = 0.f;
#pragma unroll
    for (int k = 0; k < K_; k++) {
        const float* sp = proj + (size_t)sel[k] * D_;
        a0 += sp[tid]; a1 += sp[tid + 256];
    }
    agg_bf[(size_t)be * D_ + tid] = f2bf(a0 * 0.125f);
    agg_bf[(size_t)be * D_ + tid + 256] = f2bf(a1 * 0.125f);
}

// out = LN(x + y [+ y2])*g + b (optional *mask); y has row stride ystride,
// y2 (nullable) = split-K partial at stride D_. eids (nullable): x-row index
// indirection, x-row = eids[t] (R9 — reads proj directly, values identical
// to the old states0 copy). f32 out nullable (R5).
__global__ void add_ln_kernel(const float* __restrict__ x, const int* __restrict__ eids,
                              const float* __restrict__ y,
                              int ystride, const float* __restrict__ y2,
                              const float* __restrict__ g,
                              const float* __restrict__ bb, const float* __restrict__ mask,
                              float* __restrict__ out, unsigned short* __restrict__ out_bf) {
    int t = blockIdx.x, tid = threadIdx.x;
    int xrow = eids ? eids[t] : t;
    const float* xr = x + (size_t)xrow * D_;
    const float* yr = y + (size_t)t * ystride;
    float x0 = xr[tid] + yr[tid];
    float x1 = xr[tid + 256] + yr[tid + 256];
    if (y2) {
        const float* y2r = y2 + (size_t)t * D_;
        x0 += y2r[tid];
        x1 += y2r[tid + 256];
    }
    __shared__ float red[8];
    float s = x0 + x1;
#pragma unroll
    for (int off = 32; off; off >>= 1) s += __shfl_xor(s, off, 64);
    int wid = tid >> 6;
    if ((tid & 63) == 0) red[wid] = s;
    __syncthreads();
    float mean = (red[0] + red[1] + red[2] + red[3]) * (1.f / 512.f);
    float d0 = x0 - mean, d1 = x1 - mean;
    float v = d0 * d0 + d1 * d1;
#pragma unroll
    for (int off = 32; off; off >>= 1) v += __shfl_xor(v, off, 64);
    if ((tid & 63) == 0) red[4 + wid] = v;
    __syncthreads();
    float var = (red[4] + red[5] + red[6] + red[7]) * (1.f / 512.f);
    float rs = rsqrtf(var + 1e-5f);
    float mv = mask ? mask[t] : 1.f;
    float o0 = (d0 * rs * g[tid] + bb[tid]) * mv;
    float o1 = (d1 * rs * g[tid + 256] + bb[tid + 256]) * mv;
    if (out) {
        out[(size_t)t * D_ + tid] = o0;
        out[(size_t)t * D_ + tid + 256] = o1;
    }
    out_bf[(size_t)t * D_ + tid] = f2bf(o0);
    out_bf[(size_t)t * D_ + tid + 256] = f2bf(o1);
}

// Double LN: s3 = LN( (LN(x+y[+y2])*g2+b2)*mask + att ) * g1 + b1.
__global__ void dbl_ln_kernel(const float* __restrict__ x, const float* __restrict__ y,
                              const float* __restrict__ y2,
                              const float* __restrict__ g2, const float* __restrict__ b2,
                              const float* __restrict__ mask,
                              const float* __restrict__ att, int astride,
                              const float* __restrict__ g1, const float* __restrict__ b1,
                              float* __restrict__ out, unsigned short* __restrict__ out_bf) {
    int t = blockIdx.x, tid = threadIdx.x;
    const float* xr = x + (size_t)t * D_;
    const float* yr = y + (size_t)t * D_;
    float x0 = xr[tid] + yr[tid];
    float x1 = xr[tid + 256] + yr[tid + 256];
    if (y2) {
        const float* y2r = y2 + (size_t)t * D_;
        x0 += y2r[tid];
        x1 += y2r[tid + 256];
    }
    __shared__ float red[8];
    int wid = tid >> 6;
    // LN #1 (= LN2 of layer 0)
    float s = x0 + x1;
#pragma unroll
    for (int off = 32; off; off >>= 1) s += __shfl_xor(s, off, 64);
    if ((tid & 63) == 0) red[wid] = s;
    __syncthreads();
    float mean = (red[0] + red[1] + red[2] + red[3]) * (1.f / 512.f);
    float d0 = x0 - mean, d1 = x1 - mean;
    float v = d0 * d0 + d1 * d1;
#pragma unroll
    for (int off = 32; off; off >>= 1) v += __shfl_xor(v, off, 64);
    if ((tid & 63) == 0) red[4 + wid] = v;
    __syncthreads();
    float var = (red[4] + red[5] + red[6] + red[7]) * (1.f / 512.f);
    float rs = rsqrtf(var + 1e-5f);
    float mv = mask[t];
    float t0 = (d0 * rs * g2[tid] + b2[tid]) * mv;
    float t1 = (d1 * rs * g2[tid + 256] + b2[tid + 256]) * mv;
    // residual with layer-1 attention
    const float* ar = att + (size_t)t * astride;
    float y0 = t0 + ar[tid];
    float y1 = t1 + ar[tid + 256];
    __syncthreads();
    // LN #2 (= LN1 of layer 1)
    float s2 = y0 + y1;
#pragma unroll
    for (int off = 32; off; off >>= 1) s2 += __shfl_xor(s2, off, 64);
    if ((tid & 63) == 0) red[wid] = s2;
    __syncthreads();
    float mean2 = (red[0] + red[1] + red[2] + red[3]) * (1.f / 512.f);
    float e0 = y0 - mean2, e1 = y1 - mean2;
    float v2 = e0 * e0 + e1 * e1;
#pragma unroll
    for (int off = 32; off; off >>= 1) v2 += __shfl_xor(v2, off, 64);
    if ((tid & 63) == 0) red[4 + wid] = v2;
    __syncthreads();
    float var2 = (red[4] + red[5] + red[6] + red[7]) * (1.f / 512.f);
    float rs2 = rsqrtf(var2 + 1e-5f);
    float o0 = e0 * rs2 * g1[tid] + b1[tid];
    float o1 = e1 * rs2 * g1[tid + 256] + b1[tid + 256];
    out[(size_t)t * D_ + tid] = o0;
    out[(size_t)t * D_ + tid + 256] = o1;
    out_bf[(size_t)t * D_ + tid] = f2bf(o0);
    out_bf[(size_t)t * D_ + tid + 256] = f2bf(o1);
}

// Cross-attention over combined kv [T,1024]. R5-proven: 4 memory tokens per
// block -> grid = B_*H_*(M_/4) = 512; K/V slabs read once per block.
__global__ void mem_attn(const float* __restrict__ qb, const float* __restrict__ kv,
                         const float* __restrict__ mask, unsigned short* __restrict__ memb) {
    int idx = blockIdx.x;
    int b = idx & 7;
    int h = (idx >> 3) & 7;
    int mg = idx >> 6;                 // 0..7 -> tokens mg*4 .. mg*4+3
    int tid = threadIdx.x;
    __shared__ float qh[4][64];
    __shared__ float sc[4][256];
    __shared__ float redm[4][4];       // [wave][m] max partials
    __shared__ float reds[4][4];       // [wave][m] sum partials
    __shared__ float oacc[4][4][64];   // [part][m][d]

    {
        int i = tid >> 6, d = tid & 63;
        qh[i][d] = qb[(size_t)(mg * 4 + i) * D_ + h * DH_ + d];
    }
    float mk = mask[b * E_ + tid];
    __syncthreads();

    const float* kr = kv + ((size_t)(b * E_ + tid)) * 1024 + h * DH_;
    float s0 = 0.f, s1 = 0.f, s2 = 0.f, s3 = 0.f;
#pragma unroll
    for (int d = 0; d < DH_; d += 4) {
        float4 k4 = *(const float4*)(kr + d);
        s0 += k4.x * qh[0][d] + k4.y * qh[0][d + 1] + k4.z * qh[0][d + 2] + k4.w * qh[0][d + 3];
        s1 += k4.x * qh[1][d] + k4.y * qh[1][d + 1] + k4.z * qh[1][d + 2] + k4.w * qh[1][d + 3];
        s2 += k4.x * qh[2][d] + k4.y * qh[2][d + 1] + k4.z * qh[2][d + 2] + k4.w * qh[2][d + 3];
        s3 += k4.x * qh[3][d] + k4.y * qh[3][d + 1] + k4.z * qh[3][d + 2] + k4.w * qh[3][d + 3];
    }
    s0 *= 0.125f; s1 *= 0.125f; s2 *= 0.125f; s3 *= 0.125f;
    if (mk == 0.f) { s0 = s1 = s2 = s3 = -3.402823466e38f; }

    int wid = tid >> 6;
    float m0 = s0, m1 = s1, m2 = s2, m3 = s3;
#pragma unroll
    for (int off = 32; off; off >>= 1) {
        m0 = fmaxf(m0, __shfl_xor(m0, off, 64));
        m1 = fmaxf(m1, __shfl_xor(m1, off, 64));
        m2 = fmaxf(m2, __shfl_xor(m2, off, 64));
        m3 = fmaxf(m3, __shfl_xor(m3, off, 64));
    }
    if ((tid & 63) == 0) { redm[wid][0] = m0; redm[wid][1] = m1; redm[wid][2] = m2; redm[wid][3] = m3; }
    __syncthreads();
    m0 = fmaxf(fmaxf(redm[0][0], redm[1][0]), fmaxf(redm[2][0], redm[3][0]));
    m1 = fmaxf(fmaxf(redm[0][1], redm[1][1]), fmaxf(redm[2][1], redm[3][1]));
    m2 = fmaxf(fmaxf(redm[0][2], redm[1][2]), fmaxf(redm[2][2], redm[3][2]));
    m3 = fmaxf(fmaxf(redm[0][3], redm[1][3]), fmaxf(redm[2][3], redm[3][3]));
    float p0 = expf(s0 - m0), p1 = expf(s1 - m1), p2 = expf(s2 - m2), p3 = expf(s3 - m3);
    float u0 = p0, u1 = p1, u2 = p2, u3 = p3;
#pragma unroll
    for (int off = 32; off; off >>= 1) {
        u0 += __shfl_xor(u0, off, 64);
        u1 += __shfl_xor(u1, off, 64);
        u2 += __shfl_xor(u2, off, 64);
        u3 += __shfl_xor(u3, off, 64);
    }
    if ((tid & 63) == 0) { reds[wid][0] = u0; reds[wid][1] = u1; reds[wid][2] = u2; reds[wid][3] = u3; }
    __syncthreads();
    u0 = reds[0][0] + reds[1][0] + reds[2][0] + reds[3][0];
    u1 = reds[0][1] + reds[1][1] + reds[2][1] + reds[3][1];
    u2 = reds[0][2] + reds[1][2] + reds[2][2] + reds[3][2];
    u3 = reds[0][3] + reds[1][3] + reds[2][3] + reds[3][3];
    sc[0][tid] = p0 / u0;
    sc[1][tid] = p1 / u1;
    sc[2][tid] = p2 / u2;
    sc[3][tid] = p3 / u3;
    __syncthreads();

    int d = tid & 63, part = tid >> 6;
    const float* vcol = kv + ((size_t)(b * E_ + part * 64)) * 1024 + 512 + h * DH_ + d;
    float a0 = 0.f, a1 = 0.f, a2 = 0.f, a3 = 0.f;
#pragma unroll 8
    for (int e = 0; e < 64; e++) {
        float vv = vcol[(size_t)e * 1024];
        a0 += sc[0][part * 64 + e] * vv;
        a1 += sc[1][part * 64 + e] * vv;
        a2 += sc[2][part * 64 + e] * vv;
        a3 += sc[3][part * 64 + e] * vv;
    }
    oacc[part][0][d] = a0;
    oacc[part][1][d] = a1;
    oacc[part][2][d] = a2;
    oacc[part][3][d] = a3;
    __syncthreads();
    if (part == 0) {
#pragma unroll
        for (int i = 0; i < 4; i++)
            memb[((size_t)(b * M_ + mg * 4 + i)) * D_ + h * DH_ + d] =
                f2bf(oacc[0][i][d] + oacc[1][i][d] + oacc[2][i][d] + oacc[3][i][d]);
    }
}

extern "C" void kernel_launch(void* const* d_in, const int* in_sizes, int n_in,
                              void* d_out, int out_size, void* d_ws, size_t ws_size,
                              hipStream_t stream) {
    const int*   edge_rel_ids     = (const int*)d_in[0];
    const int*   neighbor_rel_ids = (const int*)d_in[1];
    const float* edge_mask        = (const float*)d_in[2];
    const float* rel_emb          = (const float*)d_in[3];
    const float* rp_w             = (const float*)d_in[4];
    const float* rp_b             = (const float*)d_in[5];
    const float* ly_vw            = (const float*)d_in[6];
    const float* ly_vb            = (const float*)d_in[7];
    const float* ly_ow            = (const float*)d_in[8];
    const float* ly_ob            = (const float*)d_in[9];
    const float* ly_n1g           = (const float*)d_in[10];
    const float* ly_n1b           = (const float*)d_in[11];
    const float* ly_n2g           = (const float*)d_in[12];
    const float* ly_n2b           = (const float*)d_in[13];
    const float* ly_w1            = (const float*)d_in[14];
    const float* ly_b1            = (const float*)d_in[15];
    const float* ly_w2            = (const float*)d_in[16];
    const float* ly_b2            = (const float*)d_in[17];
    const float* mem_q            = (const float*)d_in[18];
    const float* t_qw             = (const float*)d_in[19];
    const float* t_qb             = (const float*)d_in[20];
    const float* t_kw             = (const float*)d_in[21];
    const float* t_kb             = (const float*)d_in[22];
    const float* t_vw             = (const float*)d_in[23];
    const float* t_vb             = (const float*)d_in[24];
    const float* t_ow             = (const float*)d_in[25];
    const float* t_ob             = (const float*)d_in[26];
    const float* proj_w           = (const float*)d_in[27];
    const float* proj_b           = (const float*)d_in[28];
    float* out = (float*)d_out;
    (void)ws_size; (void)in_sizes; (void)n_in; (void)out_size;

    char* ws = (char*)d_ws;
    size_t off = 0;
    auto allocf = [&](size_t n) { float* p = (float*)(ws + off); off += ((n * 4 + 255) & ~(size_t)255); return p; };
    auto allocb = [&](size_t n) { unsigned short* p = (unsigned short*)(ws + off); off += ((n * 2 + 255) & ~(size_t)255); return p; };

    const int T = B_ * E_;

    float* states  = allocf((size_t)T * D_);   // states3 (dbl_ln out)
    float* statesX = allocf((size_t)T * D_);   // states1 (LN1 out)
    float* proj    = allocf((size_t)R_ * D_);
    float* tmpB    = allocf((size_t)T * D_ * 2);  // 2 split-K partials
    float* attnall = allocf((size_t)T * 2 * D_);
    float* qbuf    = allocf((size_t)M_ * D_);
    float* bfuse   = allocf(2 * D_);
    float* kvb     = allocf(2 * D_);
    float* flags   = allocf(B_);
    float* kvbuf   = attnall;   // alias: attnall dead after dbl_ln consumed l1 slice

    unsigned short* rel_bf  = allocb((size_t)2048 * RD_);   // rows padded to 2048
    unsigned short* rpw_bf  = allocb((size_t)D_ * RD_);
    unsigned short* agg_bf  = allocb((size_t)T * D_);
    unsigned short* st_bf   = allocb((size_t)T * D_);
    unsigned short* ff1_bf  = allocb((size_t)T * 4 * D_);
    unsigned short* vwT_bf  = allocb((size_t)L_ * D_ * D_);
    unsigned short* ow_bf   = allocb((size_t)L_ * D_ * D_);
    unsigned short* wfuse   = allocb((size_t)L_ * D_ * D_);
    unsigned short* w1_bf   = allocb((size_t)L_ * 4 * D_ * D_);
    unsigned short* w2_bf   = allocb((size_t)L_ * 4 * D_ * D_);
    unsigned short* kvw_bf  = allocb((size_t)2 * D_ * D_);
    unsigned short* tow_bf  = allocb((size_t)D_ * D_);
    unsigned short* pw_bf   = allocb((size_t)HL_ * D_);
    unsigned short* memb_bf = allocb((size_t)B_ * M_ * D_);
    unsigned short* mem2_bf = allocb((size_t)B_ * M_ * D_);

    // ---- 1. prep ----
    PrepArgs a;
    int sizes[9] = { R_ * RD_, D_ * RD_, L_ * D_ * D_, L_ * 4 * D_ * D_,
                     L_ * 4 * D_ * D_, D_ * D_, D_ * D_, D_ * D_, HL_ * D_ };
    const float* srcs[9] = { rel_emb, rp_w, ly_ow, ly_w1, ly_w2, t_kw, t_vw, t_ow, proj_w };
    unsigned short* dsts[9] = { rel_bf, rpw_bf, ow_bf, w1_bf, w2_bf,
                                kvw_bf, kvw_bf + (size_t)D_ * D_, tow_bf, pw_bf };
    int cum = 0;
    for (int i = 0; i < 9; i++) {
        a.src[i] = srcs[i]; a.dst[i] = dsts[i];
        a.cum4[i] = cum; cum += sizes[i] / 4;
    }
    a.cum4[9] = cum;
    a.total4 = cum;
    a.nb_cvt = (cum + 255) / 256;
    a.ly_vw = ly_vw; a.vwT = vwT_bf;
    a.ly_ow = ly_ow; a.ly_vb = ly_vb; a.ly_ob = ly_ob; a.bfuse = bfuse;
    a.t_kb = t_kb; a.t_vb = t_vb; a.kvb = kvb;
    a.edge_mask = edge_mask; a.flags = flags;
    a.mem_q = mem_q; a.t_qw = t_qw; a.t_qb = t_qb; a.qbuf = qbuf;
    int nblk = a.nb_cvt + 512 + 256 + 1 + 4096;
    prep_all<<<nblk, 256, 0, stream>>>(a);

    // ---- 2. proj + wfuse merged ----
    projwfuse_kernel<<<760, 256, 0, stream>>>(rel_bf, rpw_bf, rp_b, proj,
                                              ow_bf, vwT_bf, wfuse);

    // ---- 3. sims + top-k + aggregate ----
    sim_topk_agg<<<T, 256, 0, stream>>>(edge_rel_ids, neighbor_rel_ids, proj, agg_bf);

    // ---- 4. attn (both layers) = agg @ wfuse^T + bfuse  [2048,1024] ----
    gemm_mfma<64, 64, 0, 0, 1, 0><<<dim3(16, 32), 256, 0, stream>>>(
        agg_bf, wfuse, bfuse, attnall, T, 2 * D_, D_, nullptr);

    // ---- 5. LN1(l0): states1 = LN(proj[eid] + attnall_l0) ----
    add_ln_kernel<<<T, 256, 0, stream>>>(proj, edge_rel_ids, attnall, 2 * D_, nullptr,
                                         ly_n1g, ly_n1b, nullptr, statesX, st_bf);
    // ---- 6. ff1(l0), 64x128: 512 blocks ----
    gemm_mfma<64, 128, 1, 1, 1, 0><<<dim3(16, 32), 256, 0, stream>>>(
        st_bf, w1_bf, ly_b1, ff1_bf, T, 4 * D_, D_, nullptr);
    // ---- 7. ff2(l0), 64x64 split-K x2: 512 blocks ----
    gemm_mfma<64, 64, 0, 0, 1, 0, 2><<<dim3(8, 32, 2), 256, 0, stream>>>(
        ff1_bf, w2_bf, ly_b2, tmpB, T, D_, 4 * D_, nullptr);
    // ---- 8. LN2(l0)+LN1(l1) fused ----
    dbl_ln_kernel<<<T, 256, 0, stream>>>(statesX, tmpB, tmpB + (size_t)T * D_,
                                         ly_n2g, ly_n2b, edge_mask,
                                         attnall + D_, 2 * D_, ly_n1g + D_, ly_n1b + D_,
                                         states, st_bf);
    // ---- 9. ff1(l1), 64x128 ----
    gemm_mfma<64, 128, 1, 1, 1, 0><<<dim3(16, 32), 256, 0, stream>>>(
        st_bf, w1_bf + (size_t)4 * D_ * D_, ly_b1 + 4 * D_, ff1_bf, T, 4 * D_, D_, nullptr);
    // ---- 10. ff2(l1), 64x64 split-K x2 ----
    gemm_mfma<64, 64, 0, 0, 1, 0, 2><<<dim3(8, 32, 2), 256, 0, stream>>>(
        ff1_bf, w2_bf + (size_t)4 * D_ * D_, ly_b2 + D_, tmpB, T, D_, 4 * D_, nullptr);
    // ---- 11. LN2(l1): states4 = LN(states3 + ff0 + ff1)*mask (f32 out dead) ----
    add_ln_kernel<<<T, 256, 0, stream>>>(states, nullptr, tmpB, D_, tmpB + (size_t)T * D_,
                                         ly_n2g + D_, ly_n2b + D_, edge_mask,
                                         nullptr, st_bf);
    // ---- 12. kv projection [2048,1024] ----
    gemm_mfma<64, 64, 0, 0, 1, 0><<<dim3(16, 32), 256, 0, stream>>>(
        st_bf, kvw_bf, kvb, kvbuf, T, 2 * D_, D_, nullptr);
    // ---- 13. memory cross-attention, 4 tokens/block (512 blocks) ----
    mem_attn<<<B_ * H_ * (M_ / 4), 256, 0, stream>>>(qbuf, kvbuf, edge_mask, memb_bf);
    // ---- 14. t_ow projection + no-edge zeroing via flags ----
    gemm_mfma<32, 64, 0, 1, 1, 1><<<dim3(8, 8), 256, 0, stream>>>(
        memb_bf, tow_bf, t_ob, mem2_bf, B_ * M_, D_, D_, flags);
    // ---- 15. final LLM projection ----
    gemm_mfma<32, 64, 0, 0, 1, 0><<<dim3(64, 8), 256, 0, stream>>>(
        mem2_bf, pw_bf, proj_b, out, B_ * M_, HL_, D_, nullptr);
}